// Round 4
// baseline (698.079 us; speedup 1.0000x reference)
//
#include <hip/hip_runtime.h>

// BiMambaBlock on gfx950. Inputs fp32 (bf16-valued dataset), OUTPUT fp32
// (reference output dtype). Internal: GEMMs bf16 MFMA 16x16x32, 128x128 tile,
// BK=32, fp32 accumulate; elementwise stages all fp32.
// Round 4 diff vs round 3: fp32 d_out (this was the 6.86 bug); fp32 direct
// reads everywhere except GEMM operands; cvt only for in_w/out_w.

typedef unsigned short u16;
typedef unsigned int u32;
typedef __bf16 bf16x8 __attribute__((ext_vector_type(8)));
typedef float f32x4 __attribute__((ext_vector_type(4)));
typedef u32 u32x4 __attribute__((ext_vector_type(4)));

#define L_SEQ 1024
#define DM 768
#define DI 1536
#define DS 16
#define DTR 48
#define M_TOK 2048

__device__ __forceinline__ u16 f2bf(float f) {
  union { float f; u32 i; } v; v.f = f;
  u32 r = v.i + 0x7fffu + ((v.i >> 16) & 1u);   // RNE
  return (u16)(r >> 16);
}

// ---------------- fp32 -> bf16 convert (GEMM weights) ----------------------
__launch_bounds__(256)
__global__ void k_cvt(const float* __restrict__ in, u16* __restrict__ out, int n) {
  const int i = blockIdx.x * 256 + threadIdx.x;
  if (i < n) out[i] = f2bf(in[i]);
}

// ---------------- LayerNorm: x fp32 -> x0 bf16, one block per token --------
__launch_bounds__(256)
__global__ void k_ln(const float* __restrict__ x, const float* __restrict__ g,
                     const float* __restrict__ b, u16* __restrict__ x0) {
  const int tok = blockIdx.x;
  const int tid = threadIdx.x;
  const float e0 = x[tok * DM + tid];
  const float e1 = x[tok * DM + tid + 256];
  const float e2 = x[tok * DM + tid + 512];
  float s = e0 + e1 + e2;
  float s2 = e0 * e0 + e1 * e1 + e2 * e2;
#pragma unroll
  for (int off = 1; off < 64; off <<= 1) {
    s += __shfl_xor(s, off, 64);
    s2 += __shfl_xor(s2, off, 64);
  }
  __shared__ float rs[4], rq[4];
  const int wave = tid >> 6, lane = tid & 63;
  if (lane == 0) { rs[wave] = s; rq[wave] = s2; }
  __syncthreads();
  s = rs[0] + rs[1] + rs[2] + rs[3];
  s2 = rq[0] + rq[1] + rq[2] + rq[3];
  const float mean = s * (1.0f / DM);
  const float var = s2 * (1.0f / DM) - mean * mean;
  const float inv = rsqrtf(var + 1e-5f);
  x0[tok * DM + tid]       = f2bf((e0 - mean) * inv * g[tid]       + b[tid]);
  x0[tok * DM + tid + 256] = f2bf((e1 - mean) * inv * g[tid + 256] + b[tid + 256]);
  x0[tok * DM + tid + 512] = f2bf((e2 - mean) * inv * g[tid + 512] + b[tid + 512]);
}

// ---------------- weight padding (fp32 in -> bf16 padded out) --------------
// xproj (80x1536) -> (128x1536) zero-padded rows. grid (6,128,2)
__launch_bounds__(256)
__global__ void k_pad_xproj(const float* __restrict__ w0, const float* __restrict__ w1,
                            u16* __restrict__ o0, u16* __restrict__ o1) {
  const int dir = blockIdx.z;
  const float* w = dir ? w1 : w0;
  u16* o = dir ? o1 : o0;
  const int col = blockIdx.x * 256 + threadIdx.x;
  const int row = blockIdx.y;
  o[row * DI + col] = (row < 80) ? f2bf(w[row * DI + col]) : (u16)0;
}
// dt_w (1536x48) -> (1536x64) zero-padded cols. grid (384,2)
__launch_bounds__(256)
__global__ void k_pad_dtw(const float* __restrict__ w0, const float* __restrict__ w1,
                          u16* __restrict__ o0, u16* __restrict__ o1) {
  const int dir = blockIdx.y;
  const float* w = dir ? w1 : w0;
  u16* o = dir ? o1 : o0;
  const int idx = blockIdx.x * 256 + threadIdx.x;
  const int row = idx >> 6, col = idx & 63;
  o[idx] = (col < DTR) ? f2bf(w[row * DTR + col]) : (u16)0;
}

// ---------------- GEMM: C[m,n] = sum_k A[m,k]*W[n,k], bf16 in / fp32 out ---
// MODE 0: plain fp32 store.
// MODE 1: fp32 store + bf16 dtin[m*64+n] for n<64 (zero for n>=48).
// MODE 2: fp32 store of softplus(acc + bias[n]), bias fp32.
template <int MODE>
__launch_bounds__(256)
__global__ void k_gemm(const u16* __restrict__ A0, const u16* __restrict__ A1,
                       const u16* __restrict__ W0, const u16* __restrict__ W1,
                       float* __restrict__ C0, float* __restrict__ C1,
                       const float* __restrict__ b0, const float* __restrict__ b1,
                       u16* __restrict__ aux0, u16* __restrict__ aux1,
                       int N, int K, int flip1) {
  const int dir = blockIdx.z;
  const u16* A = dir ? A1 : A0;
  const u16* W = dir ? W1 : W0;
  float* C = dir ? C1 : C0;
  const float* bias = dir ? b1 : b0;
  u16* aux = dir ? aux1 : aux0;
  const int doflip = flip1 & dir;

  __shared__ __align__(16) u16 sA[128 * 32];
  __shared__ __align__(16) u16 sB[128 * 32];

  const int tid = threadIdx.x;
  const int lane = tid & 63, wave = tid >> 6;
  const int m0 = blockIdx.y * 128, n0 = blockIdx.x * 128;

  const f32x4 vzero = {0.f, 0.f, 0.f, 0.f};
  f32x4 acc[4][4];
#pragma unroll
  for (int i = 0; i < 4; ++i)
#pragma unroll
    for (int j = 0; j < 4; ++j) acc[i][j] = vzero;

  const int lrow = lane & 15, kseg = lane >> 4;
  const int wm = (wave >> 1) * 64, wn = (wave & 1) * 64;

  for (int kt = 0; kt < K; kt += 32) {
    u32x4 va[2], vb[2];
#pragma unroll
    for (int c = 0; c < 2; ++c) {
      const int q = c * 256 + tid;
      int rA = m0 + (q >> 2);
      if (doflip) rA ^= (L_SEQ - 1);
      const int kc = kt + (q & 3) * 8;
      va[c] = *(const u32x4*)(A + (size_t)rA * K + kc);
      vb[c] = *(const u32x4*)(W + (size_t)(n0 + (q >> 2)) * K + kc);
    }
    __syncthreads();  // previous iteration's LDS reads drained (barrier waitcnt)
#pragma unroll
    for (int c = 0; c < 2; ++c) {
      const int q = c * 256 + tid;
      *(u32x4*)&sA[q * 8] = va[c];
      *(u32x4*)&sB[q * 8] = vb[c];
    }
    __syncthreads();
    bf16x8 af[4], bfv[4];
#pragma unroll
    for (int i = 0; i < 4; ++i)
      af[i] = *(const bf16x8*)&sA[(wm + i * 16 + lrow) * 32 + kseg * 8];
#pragma unroll
    for (int j = 0; j < 4; ++j)
      bfv[j] = *(const bf16x8*)&sB[(wn + j * 16 + lrow) * 32 + kseg * 8];
#pragma unroll
    for (int i = 0; i < 4; ++i)
#pragma unroll
      for (int j = 0; j < 4; ++j)
        acc[i][j] = __builtin_amdgcn_mfma_f32_16x16x32_bf16(af[i], bfv[j], acc[i][j], 0, 0, 0);
  }

  // C/D layout: col = lane&15, row = (lane>>4)*4 + reg
  const int erow = (lane >> 4) * 4, ecol = lane & 15;
#pragma unroll
  for (int i = 0; i < 4; ++i) {
#pragma unroll
    for (int j = 0; j < 4; ++j) {
#pragma unroll
      for (int r = 0; r < 4; ++r) {
        const int m = m0 + wm + i * 16 + erow + r;
        const int n = n0 + wn + j * 16 + ecol;
        float v = acc[i][j][r];
        if (MODE == 2) {
          const float xv = v + bias[n];
          v = fmaxf(xv, 0.f) + log1pf(__expf(-fabsf(xv)));  // stable softplus
        }
        C[(size_t)m * N + n] = v;
        if (MODE == 1) {
          if (n < 64) aux[m * 64 + n] = f2bf(n < DTR ? v : 0.f);
        }
      }
    }
  }
}

// ---------------- depthwise causal conv (k=4) + SiLU -> xc bf16 -----------
__launch_bounds__(256)
__global__ void k_conv(const float* __restrict__ xz0, const float* __restrict__ xz1,
                       u16* __restrict__ xc0, u16* __restrict__ xc1,
                       const float* __restrict__ w0, const float* __restrict__ w1,
                       const float* __restrict__ cb0, const float* __restrict__ cb1) {
  const int dir = blockIdx.z;
  const float* xz = dir ? xz1 : xz0;
  u16* xc = dir ? xc1 : xc0;
  const float* w = dir ? w1 : w0;
  const float* cb = dir ? cb1 : cb0;
  const int d = blockIdx.x * 256 + threadIdx.x;
  const int tok = blockIdx.y;
  const int l = tok & (L_SEQ - 1);
  float s = cb[d];
#pragma unroll
  for (int j = 0; j < 4; ++j) {
    const int ls = l - 3 + j;
    if (ls >= 0) s += w[d * 4 + j] * xz[(size_t)(tok - 3 + j) * (2 * DI) + d];
  }
  const float r = s / (1.f + __expf(-s));
  xc[(size_t)tok * DI + d] = f2bf(r);
}

// ---------------- selective scan ------------------------------------------
// thread = (d,n); 64-thr blocks (4 d-channels); grid (384, B=2, dirs=2).
__launch_bounds__(64)
__global__ void k_scan(const float* __restrict__ dl0, const float* __restrict__ dl1,
                       const u16* __restrict__ xc0, const u16* __restrict__ xc1,
                       const float* __restrict__ dbc0, const float* __restrict__ dbc1,
                       const float* __restrict__ xz0, const float* __restrict__ xz1,
                       const float* __restrict__ al0, const float* __restrict__ al1,
                       const float* __restrict__ dp0, const float* __restrict__ dp1,
                       u16* __restrict__ y0, u16* __restrict__ y1) {
  const int dir = blockIdx.z;
  const float* delta = dir ? dl1 : dl0;
  const u16* xc = dir ? xc1 : xc0;
  const float* dbc = dir ? dbc1 : dbc0;
  const float* xz = dir ? xz1 : xz0;
  const float* alog = dir ? al1 : al0;
  const float* dpp = dir ? dp1 : dp0;
  u16* y = dir ? y1 : y0;

  const int bb = blockIdx.y;
  const int tid = threadIdx.x;
  const int dloc = tid >> 4, n = tid & 15;
  const int d = blockIdx.x * 4 + dloc;
  const float Af = -__expf(alog[d * DS + n]);
  const float Dv = dpp[d];

  const size_t tb = (size_t)bb * L_SEQ;
  float h = 0.f;
  float dlt = delta[tb * DI + d];
  float xcv = (float)(((const __bf16*)xc)[tb * DI + d]);
  float Bv = dbc[tb * 128 + 48 + n];
  float Cv = dbc[tb * 128 + 64 + n];
  float zv = xz[tb * (2 * DI) + DI + d];
  for (int l = 0; l < L_SEQ; ++l) {
    float dltn = 0.f, xcvn = 0.f, Bvn = 0.f, Cvn = 0.f, zvn = 0.f;
    if (l < L_SEQ - 1) {
      const size_t t1 = tb + l + 1;
      dltn = delta[t1 * DI + d];
      xcvn = (float)(((const __bf16*)xc)[t1 * DI + d]);
      Bvn = dbc[t1 * 128 + 48 + n];
      Cvn = dbc[t1 * 128 + 64 + n];
      zvn = xz[t1 * (2 * DI) + DI + d];
    }
    const float dA = __expf(dlt * Af);
    h = fmaf(dA, h, dlt * Bv * xcv);
    float p = h * Cv;  // reduction does not feed recurrence -> pipelines
    p += __shfl_xor(p, 1, 64);
    p += __shfl_xor(p, 2, 64);
    p += __shfl_xor(p, 4, 64);
    p += __shfl_xor(p, 8, 64);
    if (n == 0) {
      const float yv = p + xcv * Dv;
      const float sz = zv / (1.f + __expf(-zv));
      y[(tb + l) * DI + d] = f2bf(yv * sz);
    }
    dlt = dltn; xcv = xcvn; Bv = Bvn; Cv = Cvn; zv = zvn;
  }
}

// ---------------- final: out = x + fwd + flip(bwd), fp32 out --------------
__launch_bounds__(256)
__global__ void k_final(const float* __restrict__ x, const float* __restrict__ g0,
                        const float* __restrict__ g1, float* __restrict__ out) {
  const int c = blockIdx.x * 256 + threadIdx.x;
  const int tok = blockIdx.y;
  const int ftok = tok ^ (L_SEQ - 1);
  const size_t i = (size_t)tok * DM + c;
  out[i] = x[i] + g0[i] + g1[(size_t)ftok * DM + c];
}

extern "C" void kernel_launch(void* const* d_in, const int* in_sizes, int n_in,
                              void* d_out, int out_size, void* d_ws, size_t ws_size,
                              hipStream_t stream) {
  (void)n_in; (void)out_size;
  const float* x      = (const float*)d_in[0];
  const float* ln_g   = (const float*)d_in[1];
  const float* ln_b   = (const float*)d_in[2];
  const float* in_w_f[2]  = {(const float*)d_in[3],  (const float*)d_in[12]};
  const float* conv_w[2]  = {(const float*)d_in[4],  (const float*)d_in[13]};
  const float* conv_b[2]  = {(const float*)d_in[5],  (const float*)d_in[14]};
  const float* xproj_w[2] = {(const float*)d_in[6],  (const float*)d_in[15]};
  const float* dt_w[2]    = {(const float*)d_in[7],  (const float*)d_in[16]};
  const float* dt_b[2]    = {(const float*)d_in[8],  (const float*)d_in[17]};
  const float* A_log[2]   = {(const float*)d_in[9],  (const float*)d_in[18]};
  const float* Dp[2]      = {(const float*)d_in[10], (const float*)d_in[19]};
  const float* out_w_f[2] = {(const float*)d_in[11], (const float*)d_in[20]};

  char* ws = (char*)d_ws;
  size_t off = 0;
  auto alloc = [&](size_t bytes) {
    void* p = ws + off;
    off = (off + bytes + 255) & ~(size_t)255;
    return p;
  };

  u16* inw[2];  for (int i = 0; i < 2; ++i) inw[i]  = (u16*)alloc((size_t)2 * DI * DM * 2);
  u16* outw[2]; for (int i = 0; i < 2; ++i) outw[i] = (u16*)alloc((size_t)DM * DI * 2);
  u16* x0 = (u16*)alloc((size_t)M_TOK * DM * 2);
  float* xz[2];   for (int i = 0; i < 2; ++i) xz[i]   = (float*)alloc((size_t)M_TOK * 2 * DI * 4);
  u16* xc[2];     for (int i = 0; i < 2; ++i) xc[i]   = (u16*)alloc((size_t)M_TOK * DI * 2);
  float* dbc[2];  for (int i = 0; i < 2; ++i) dbc[i]  = (float*)alloc((size_t)M_TOK * 128 * 4);
  u16* dtin[2];   for (int i = 0; i < 2; ++i) dtin[i] = (u16*)alloc((size_t)M_TOK * 64 * 2);
  float* dlt[2];  for (int i = 0; i < 2; ++i) dlt[i]  = (float*)alloc((size_t)M_TOK * DI * 4);
  u16* yb[2];     for (int i = 0; i < 2; ++i) yb[i]   = (u16*)alloc((size_t)M_TOK * DI * 2);
  float* gout[2]; for (int i = 0; i < 2; ++i) gout[i] = (float*)alloc((size_t)M_TOK * DM * 4);
  u16* xpw[2];    for (int i = 0; i < 2; ++i) xpw[i]  = (u16*)alloc((size_t)128 * DI * 2);
  u16* dtwp[2];   for (int i = 0; i < 2; ++i) dtwp[i] = (u16*)alloc((size_t)DI * 64 * 2);

  if (off > ws_size) return;  // sentinel: zero output -> absmax 4.97 diag

  for (int i = 0; i < 2; ++i) {
    k_cvt<<<dim3((2 * DI * DM + 255) / 256), dim3(256), 0, stream>>>(in_w_f[i], inw[i], 2 * DI * DM);
    k_cvt<<<dim3((DM * DI + 255) / 256), dim3(256), 0, stream>>>(out_w_f[i], outw[i], DM * DI);
  }

  k_ln<<<dim3(M_TOK), dim3(256), 0, stream>>>(x, ln_g, ln_b, x0);
  k_pad_xproj<<<dim3(6, 128, 2), dim3(256), 0, stream>>>(xproj_w[0], xproj_w[1], xpw[0], xpw[1]);
  k_pad_dtw<<<dim3(384, 2), dim3(256), 0, stream>>>(dt_w[0], dt_w[1], dtwp[0], dtwp[1]);
  // in-proj: xz = x0 @ in_w^T (dir1 reads row^1023)
  k_gemm<0><<<dim3(24, 16, 2), dim3(256), 0, stream>>>(
      x0, x0, inw[0], inw[1], xz[0], xz[1], nullptr, nullptr, nullptr, nullptr,
      2 * DI, DM, 1);
  k_conv<<<dim3(6, M_TOK, 2), dim3(256), 0, stream>>>(
      xz[0], xz[1], xc[0], xc[1], conv_w[0], conv_w[1], conv_b[0], conv_b[1]);
  // x-proj: dbc = xc @ xproj^T (N padded 128), fused dtin extraction
  k_gemm<1><<<dim3(1, 16, 2), dim3(256), 0, stream>>>(
      xc[0], xc[1], xpw[0], xpw[1], dbc[0], dbc[1], nullptr, nullptr, dtin[0], dtin[1],
      128, DI, 0);
  // dt-proj: delta = softplus(dtin @ dt_w^T + dt_b) (K padded 64)
  k_gemm<2><<<dim3(12, 16, 2), dim3(256), 0, stream>>>(
      dtin[0], dtin[1], dtwp[0], dtwp[1], dlt[0], dlt[1], dt_b[0], dt_b[1], nullptr, nullptr,
      DI, 64, 0);
  k_scan<<<dim3(384, 2, 2), dim3(64), 0, stream>>>(
      dlt[0], dlt[1], xc[0], xc[1], dbc[0], dbc[1], xz[0], xz[1],
      A_log[0], A_log[1], Dp[0], Dp[1], yb[0], yb[1]);
  // out-proj: gout = y @ out_w^T
  k_gemm<0><<<dim3(6, 16, 2), dim3(256), 0, stream>>>(
      yb[0], yb[1], outw[0], outw[1], gout[0], gout[1], nullptr, nullptr, nullptr, nullptr,
      DM, DI, 0);
  k_final<<<dim3(3, M_TOK), dim3(256), 0, stream>>>(x, gout[0], gout[1], (float*)d_out);
}

// Round 5
// 574.866 us; speedup vs baseline: 1.2143x; 1.2143x over previous
//
#include <hip/hip_runtime.h>

// BiMambaBlock on gfx950. Inputs fp32 (bf16-valued), output fp32.
// GEMMs: bf16 MFMA 16x16x32, 128x128 tile, BK=32, async global_load_lds x16.
// Scan: 256-thr blocks (16d x 16n), 64-step LDS-staged time chunks.
// Round 5 diff vs round 4: chunked LDS scan (was 4x over-fetch + latency
// bound, 396us); async GEMM staging restored.

typedef unsigned short u16;
typedef unsigned int u32;
typedef __bf16 bf16x8 __attribute__((ext_vector_type(8)));
typedef float f32x4 __attribute__((ext_vector_type(4)));
typedef u32 u32x4 __attribute__((ext_vector_type(4)));

#define L_SEQ 1024
#define DM 768
#define DI 1536
#define DS 16
#define DTR 48
#define M_TOK 2048

__device__ __forceinline__ float bf2f(u16 u) {
  union { u32 i; float f; } v; v.i = ((u32)u) << 16; return v.f;
}
__device__ __forceinline__ u16 f2bf(float f) {
  union { float f; u32 i; } v; v.f = f;
  u32 r = v.i + 0x7fffu + ((v.i >> 16) & 1u);   // RNE
  return (u16)(r >> 16);
}

// async global->LDS, 16B/lane; lds dest = wave-uniform base + lane*16
__device__ __forceinline__ void llds16(const void* g, void* l) {
  __builtin_amdgcn_global_load_lds((__attribute__((address_space(1))) void*)g,
                                   (__attribute__((address_space(3))) void*)l, 16, 0, 0);
}

// ---------------- fp32 -> bf16 convert (GEMM weights) ----------------------
__launch_bounds__(256)
__global__ void k_cvt(const float* __restrict__ in, u16* __restrict__ out, int n) {
  const int i = blockIdx.x * 256 + threadIdx.x;
  if (i < n) out[i] = f2bf(in[i]);
}

// ---------------- LayerNorm: x fp32 -> x0 bf16, one block per token --------
__launch_bounds__(256)
__global__ void k_ln(const float* __restrict__ x, const float* __restrict__ g,
                     const float* __restrict__ b, u16* __restrict__ x0) {
  const int tok = blockIdx.x;
  const int tid = threadIdx.x;
  const float e0 = x[tok * DM + tid];
  const float e1 = x[tok * DM + tid + 256];
  const float e2 = x[tok * DM + tid + 512];
  float s = e0 + e1 + e2;
  float s2 = e0 * e0 + e1 * e1 + e2 * e2;
#pragma unroll
  for (int off = 1; off < 64; off <<= 1) {
    s += __shfl_xor(s, off, 64);
    s2 += __shfl_xor(s2, off, 64);
  }
  __shared__ float rs[4], rq[4];
  const int wave = tid >> 6, lane = tid & 63;
  if (lane == 0) { rs[wave] = s; rq[wave] = s2; }
  __syncthreads();
  s = rs[0] + rs[1] + rs[2] + rs[3];
  s2 = rq[0] + rq[1] + rq[2] + rq[3];
  const float mean = s * (1.0f / DM);
  const float var = s2 * (1.0f / DM) - mean * mean;
  const float inv = rsqrtf(var + 1e-5f);
  x0[tok * DM + tid]       = f2bf((e0 - mean) * inv * g[tid]       + b[tid]);
  x0[tok * DM + tid + 256] = f2bf((e1 - mean) * inv * g[tid + 256] + b[tid + 256]);
  x0[tok * DM + tid + 512] = f2bf((e2 - mean) * inv * g[tid + 512] + b[tid + 512]);
}

// ---------------- weight padding (fp32 in -> bf16 padded out) --------------
__launch_bounds__(256)
__global__ void k_pad_xproj(const float* __restrict__ w0, const float* __restrict__ w1,
                            u16* __restrict__ o0, u16* __restrict__ o1) {
  const int dir = blockIdx.z;
  const float* w = dir ? w1 : w0;
  u16* o = dir ? o1 : o0;
  const int col = blockIdx.x * 256 + threadIdx.x;
  const int row = blockIdx.y;
  o[row * DI + col] = (row < 80) ? f2bf(w[row * DI + col]) : (u16)0;
}
__launch_bounds__(256)
__global__ void k_pad_dtw(const float* __restrict__ w0, const float* __restrict__ w1,
                          u16* __restrict__ o0, u16* __restrict__ o1) {
  const int dir = blockIdx.y;
  const float* w = dir ? w1 : w0;
  u16* o = dir ? o1 : o0;
  const int idx = blockIdx.x * 256 + threadIdx.x;
  const int row = idx >> 6, col = idx & 63;
  o[idx] = (col < DTR) ? f2bf(w[row * DTR + col]) : (u16)0;
}

// ---------------- GEMM: C[m,n] = sum_k A[m,k]*W[n,k], bf16 in / fp32 out ---
// MODE 0: plain fp32 store.
// MODE 1: fp32 store + bf16 dtin[m*64+n] for n<64 (zero for n>=48).
// MODE 2: fp32 store of softplus(acc + bias[n]), bias fp32.
template <int MODE>
__launch_bounds__(256)
__global__ void k_gemm(const u16* __restrict__ A0, const u16* __restrict__ A1,
                       const u16* __restrict__ W0, const u16* __restrict__ W1,
                       float* __restrict__ C0, float* __restrict__ C1,
                       const float* __restrict__ b0, const float* __restrict__ b1,
                       u16* __restrict__ aux0, u16* __restrict__ aux1,
                       int N, int K, int flip1) {
  const int dir = blockIdx.z;
  const u16* A = dir ? A1 : A0;
  const u16* W = dir ? W1 : W0;
  float* C = dir ? C1 : C0;
  const float* bias = dir ? b1 : b0;
  u16* aux = dir ? aux1 : aux0;
  const int doflip = flip1 & dir;

  __shared__ __align__(16) u16 sA[128 * 32];
  __shared__ __align__(16) u16 sB[128 * 32];

  const int tid = threadIdx.x;
  const int lane = tid & 63, wave = tid >> 6;
  const int m0 = blockIdx.y * 128, n0 = blockIdx.x * 128;

  const f32x4 vzero = {0.f, 0.f, 0.f, 0.f};
  f32x4 acc[4][4];
#pragma unroll
  for (int i = 0; i < 4; ++i)
#pragma unroll
    for (int j = 0; j < 4; ++j) acc[i][j] = vzero;

  const int lrow = lane & 15, kseg = lane >> 4;
  const int wm = (wave >> 1) * 64, wn = (wave & 1) * 64;

  for (int kt = 0; kt < K; kt += 32) {
    __syncthreads();  // previous iteration's LDS reads done
#pragma unroll
    for (int c = 0; c < 2; ++c) {
      const int q = c * 256 + tid;
      int rA = m0 + (q >> 2);
      if (doflip) rA ^= (L_SEQ - 1);
      const int kc = kt + (q & 3) * 8;
      llds16(A + (size_t)rA * K + kc, &sA[(c * 256 + wave * 64) * 8]);
      llds16(W + (size_t)(n0 + (q >> 2)) * K + kc, &sB[(c * 256 + wave * 64) * 8]);
    }
    __syncthreads();  // vmcnt drained by barrier semantics
    bf16x8 af[4], bfv[4];
#pragma unroll
    for (int i = 0; i < 4; ++i)
      af[i] = *(const bf16x8*)&sA[(wm + i * 16 + lrow) * 32 + kseg * 8];
#pragma unroll
    for (int j = 0; j < 4; ++j)
      bfv[j] = *(const bf16x8*)&sB[(wn + j * 16 + lrow) * 32 + kseg * 8];
#pragma unroll
    for (int i = 0; i < 4; ++i)
#pragma unroll
      for (int j = 0; j < 4; ++j)
        acc[i][j] = __builtin_amdgcn_mfma_f32_16x16x32_bf16(af[i], bfv[j], acc[i][j], 0, 0, 0);
  }

  // C/D layout: col = lane&15, row = (lane>>4)*4 + reg
  const int erow = (lane >> 4) * 4, ecol = lane & 15;
#pragma unroll
  for (int i = 0; i < 4; ++i) {
#pragma unroll
    for (int j = 0; j < 4; ++j) {
#pragma unroll
      for (int r = 0; r < 4; ++r) {
        const int m = m0 + wm + i * 16 + erow + r;
        const int n = n0 + wn + j * 16 + ecol;
        float v = acc[i][j][r];
        if (MODE == 2) {
          const float xv = v + bias[n];
          v = fmaxf(xv, 0.f) + log1pf(__expf(-fabsf(xv)));  // stable softplus
        }
        C[(size_t)m * N + n] = v;
        if (MODE == 1) {
          if (n < 64) aux[m * 64 + n] = f2bf(n < DTR ? v : 0.f);
        }
      }
    }
  }
}

// ---------------- depthwise causal conv (k=4) + SiLU -> xc bf16 -----------
__launch_bounds__(256)
__global__ void k_conv(const float* __restrict__ xz0, const float* __restrict__ xz1,
                       u16* __restrict__ xc0, u16* __restrict__ xc1,
                       const float* __restrict__ w0, const float* __restrict__ w1,
                       const float* __restrict__ cb0, const float* __restrict__ cb1) {
  const int dir = blockIdx.z;
  const float* xz = dir ? xz1 : xz0;
  u16* xc = dir ? xc1 : xc0;
  const float* w = dir ? w1 : w0;
  const float* cb = dir ? cb1 : cb0;
  const int d = blockIdx.x * 256 + threadIdx.x;
  const int tok = blockIdx.y;
  const int l = tok & (L_SEQ - 1);
  float s = cb[d];
#pragma unroll
  for (int j = 0; j < 4; ++j) {
    const int ls = l - 3 + j;
    if (ls >= 0) s += w[d * 4 + j] * xz[(size_t)(tok - 3 + j) * (2 * DI) + d];
  }
  const float r = s / (1.f + __expf(-s));
  xc[(size_t)tok * DI + d] = f2bf(r);
}

// ---------------- selective scan (chunked LDS) ----------------------------
// block = 256 thr = (16 d) x (16 n); grid (DI/16=96, B=2, dirs=2).
// Per 64-step chunk: coalesced float4 staging of delta/z/B/C (+xc bf16) into
// LDS, compute 64 recurrence steps from LDS, stage y via LDS, store coalesced.
#define CH 64
__launch_bounds__(256)
__global__ void k_scan(const float* __restrict__ dl0, const float* __restrict__ dl1,
                       const u16* __restrict__ xc0, const u16* __restrict__ xc1,
                       const float* __restrict__ dbc0, const float* __restrict__ dbc1,
                       const float* __restrict__ xz0, const float* __restrict__ xz1,
                       const float* __restrict__ al0, const float* __restrict__ al1,
                       const float* __restrict__ dp0, const float* __restrict__ dp1,
                       u16* __restrict__ y0, u16* __restrict__ y1) {
  const int dir = blockIdx.z;
  const float* delta = dir ? dl1 : dl0;
  const u16* xc = dir ? xc1 : xc0;
  const float* dbc = dir ? dbc1 : dbc0;
  const float* xz = dir ? xz1 : xz0;
  const float* alog = dir ? al1 : al0;
  const float* dpp = dir ? dp1 : dp0;
  u16* y = dir ? y1 : y0;

  __shared__ float sD[CH][16];    // delta
  __shared__ float sZ[CH][16];    // z (gate)
  __shared__ float sBC[CH][32];   // B | C
  __shared__ u16 sXc[CH][16];     // xc bf16
  __shared__ u16 sY[CH][16];      // y out staging

  const int tid = threadIdx.x;
  const int dloc = tid >> 4, n = tid & 15;
  const int d0 = blockIdx.x * 16;
  const int d = d0 + dloc;
  const float Af = -__expf(alog[d * DS + n]);
  const float Dv = dpp[d];
  const size_t tb = (size_t)blockIdx.y * L_SEQ;

  // staging index maps (all 16B-aligned: d0 mult of 16)
  const int r4 = tid >> 2, c4 = (tid & 3) * 4;        // 64 rows x 4 float4
  const int r2 = (tid & 127) >> 1, c2 = (tid & 1) * 8; // 64 rows x 2 ushort8

  float h = 0.f;
  for (int t0 = 0; t0 < L_SEQ; t0 += CH) {
    // ---- stage chunk ----
    const size_t rowA = tb + t0 + r4;
    *(f32x4*)&sD[r4][c4] = *(const f32x4*)&delta[rowA * DI + d0 + c4];
    *(f32x4*)&sZ[r4][c4] = *(const f32x4*)&xz[rowA * (2 * DI) + DI + d0 + c4];
#pragma unroll
    for (int p = 0; p < 2; ++p) {
      const int idx = p * 256 + tid;
      const int rb = idx >> 3, cb = (idx & 7) * 4;
      *(f32x4*)&sBC[rb][cb] = *(const f32x4*)&dbc[(tb + t0 + rb) * 128 + 48 + cb];
    }
    if (tid < 128)
      *(u32x4*)&sXc[r2][c2] = *(const u32x4*)&xc[(tb + t0 + r2) * DI + d0 + c2];
    __syncthreads();

    // ---- 64 recurrence steps ----
#pragma unroll 8
    for (int t = 0; t < CH; ++t) {
      const float dlt = sD[t][dloc];
      const float xcv = bf2f(sXc[t][dloc]);
      const float Bv = sBC[t][n];
      const float Cv = sBC[t][16 + n];
      const float dA = __expf(dlt * Af);
      h = fmaf(dA, h, dlt * Bv * xcv);
      float p = h * Cv;
      p += __shfl_xor(p, 1, 64);
      p += __shfl_xor(p, 2, 64);
      p += __shfl_xor(p, 4, 64);
      p += __shfl_xor(p, 8, 64);
      if (n == 0) {
        const float zv = sZ[t][dloc];
        const float yv = p + xcv * Dv;
        const float sz = zv / (1.f + __expf(-zv));
        sY[t][dloc] = f2bf(yv * sz);
      }
    }
    __syncthreads();

    // ---- store y chunk (coalesced) ----
    if (tid < 128)
      *(u32x4*)&y[(tb + t0 + r2) * DI + d0 + c2] = *(const u32x4*)&sY[r2][c2];
    // next chunk's staging writes different arrays than sY; barrier at top of
    // next compute protects sD/sZ/sBC/sXc reuse.
  }
}

// ---------------- final: out = x + fwd + flip(bwd), fp32 out --------------
__launch_bounds__(256)
__global__ void k_final(const float* __restrict__ x, const float* __restrict__ g0,
                        const float* __restrict__ g1, float* __restrict__ out) {
  const int c = blockIdx.x * 256 + threadIdx.x;
  const int tok = blockIdx.y;
  const int ftok = tok ^ (L_SEQ - 1);
  const size_t i = (size_t)tok * DM + c;
  out[i] = x[i] + g0[i] + g1[(size_t)ftok * DM + c];
}

extern "C" void kernel_launch(void* const* d_in, const int* in_sizes, int n_in,
                              void* d_out, int out_size, void* d_ws, size_t ws_size,
                              hipStream_t stream) {
  (void)n_in; (void)out_size;
  const float* x      = (const float*)d_in[0];
  const float* ln_g   = (const float*)d_in[1];
  const float* ln_b   = (const float*)d_in[2];
  const float* in_w_f[2]  = {(const float*)d_in[3],  (const float*)d_in[12]};
  const float* conv_w[2]  = {(const float*)d_in[4],  (const float*)d_in[13]};
  const float* conv_b[2]  = {(const float*)d_in[5],  (const float*)d_in[14]};
  const float* xproj_w[2] = {(const float*)d_in[6],  (const float*)d_in[15]};
  const float* dt_w[2]    = {(const float*)d_in[7],  (const float*)d_in[16]};
  const float* dt_b[2]    = {(const float*)d_in[8],  (const float*)d_in[17]};
  const float* A_log[2]   = {(const float*)d_in[9],  (const float*)d_in[18]};
  const float* Dp[2]      = {(const float*)d_in[10], (const float*)d_in[19]};
  const float* out_w_f[2] = {(const float*)d_in[11], (const float*)d_in[20]};

  char* ws = (char*)d_ws;
  size_t off = 0;
  auto alloc = [&](size_t bytes) {
    void* p = ws + off;
    off = (off + bytes + 255) & ~(size_t)255;
    return p;
  };

  u16* inw[2];  for (int i = 0; i < 2; ++i) inw[i]  = (u16*)alloc((size_t)2 * DI * DM * 2);
  u16* outw[2]; for (int i = 0; i < 2; ++i) outw[i] = (u16*)alloc((size_t)DM * DI * 2);
  u16* x0 = (u16*)alloc((size_t)M_TOK * DM * 2);
  float* xz[2];   for (int i = 0; i < 2; ++i) xz[i]   = (float*)alloc((size_t)M_TOK * 2 * DI * 4);
  u16* xc[2];     for (int i = 0; i < 2; ++i) xc[i]   = (u16*)alloc((size_t)M_TOK * DI * 2);
  float* dbc[2];  for (int i = 0; i < 2; ++i) dbc[i]  = (float*)alloc((size_t)M_TOK * 128 * 4);
  u16* dtin[2];   for (int i = 0; i < 2; ++i) dtin[i] = (u16*)alloc((size_t)M_TOK * 64 * 2);
  float* dlt[2];  for (int i = 0; i < 2; ++i) dlt[i]  = (float*)alloc((size_t)M_TOK * DI * 4);
  u16* yb[2];     for (int i = 0; i < 2; ++i) yb[i]   = (u16*)alloc((size_t)M_TOK * DI * 2);
  float* gout[2]; for (int i = 0; i < 2; ++i) gout[i] = (float*)alloc((size_t)M_TOK * DM * 4);
  u16* xpw[2];    for (int i = 0; i < 2; ++i) xpw[i]  = (u16*)alloc((size_t)128 * DI * 2);
  u16* dtwp[2];   for (int i = 0; i < 2; ++i) dtwp[i] = (u16*)alloc((size_t)DI * 64 * 2);

  if (off > ws_size) return;  // sentinel: zero output -> absmax 4.97 diag

  for (int i = 0; i < 2; ++i) {
    k_cvt<<<dim3((2 * DI * DM + 255) / 256), dim3(256), 0, stream>>>(in_w_f[i], inw[i], 2 * DI * DM);
    k_cvt<<<dim3((DM * DI + 255) / 256), dim3(256), 0, stream>>>(out_w_f[i], outw[i], DM * DI);
  }

  k_ln<<<dim3(M_TOK), dim3(256), 0, stream>>>(x, ln_g, ln_b, x0);
  k_pad_xproj<<<dim3(6, 128, 2), dim3(256), 0, stream>>>(xproj_w[0], xproj_w[1], xpw[0], xpw[1]);
  k_pad_dtw<<<dim3(384, 2), dim3(256), 0, stream>>>(dt_w[0], dt_w[1], dtwp[0], dtwp[1]);
  // in-proj: xz = x0 @ in_w^T (dir1 reads row^1023)
  k_gemm<0><<<dim3(24, 16, 2), dim3(256), 0, stream>>>(
      x0, x0, inw[0], inw[1], xz[0], xz[1], nullptr, nullptr, nullptr, nullptr,
      2 * DI, DM, 1);
  k_conv<<<dim3(6, M_TOK, 2), dim3(256), 0, stream>>>(
      xz[0], xz[1], xc[0], xc[1], conv_w[0], conv_w[1], conv_b[0], conv_b[1]);
  // x-proj: dbc = xc @ xproj^T (N padded 128), fused dtin extraction
  k_gemm<1><<<dim3(1, 16, 2), dim3(256), 0, stream>>>(
      xc[0], xc[1], xpw[0], xpw[1], dbc[0], dbc[1], nullptr, nullptr, dtin[0], dtin[1],
      128, DI, 0);
  // dt-proj: delta = softplus(dtin @ dt_w^T + dt_b) (K padded 64)
  k_gemm<2><<<dim3(12, 16, 2), dim3(256), 0, stream>>>(
      dtin[0], dtin[1], dtwp[0], dtwp[1], dlt[0], dlt[1], dt_b[0], dt_b[1], nullptr, nullptr,
      DI, 64, 0);
  k_scan<<<dim3(96, 2, 2), dim3(256), 0, stream>>>(
      dlt[0], dlt[1], xc[0], xc[1], dbc[0], dbc[1], xz[0], xz[1],
      A_log[0], A_log[1], Dp[0], Dp[1], yb[0], yb[1]);
  // out-proj: gout = y @ out_w^T
  k_gemm<0><<<dim3(6, 16, 2), dim3(256), 0, stream>>>(
      yb[0], yb[1], outw[0], outw[1], gout[0], gout[1], nullptr, nullptr, nullptr, nullptr,
      DM, DI, 0);
  k_final<<<dim3(3, M_TOK), dim3(256), 0, stream>>>(x, gout[0], gout[1], (float*)d_out);
}

// Round 6
// 520.091 us; speedup vs baseline: 1.3422x; 1.1053x over previous
//
#include <hip/hip_runtime.h>

// BiMambaBlock on gfx950. Inputs fp32 (bf16-valued), output fp32.
// GEMMs: bf16 MFMA 16x16x32, 128x128 tile, BK=32, async global_load_lds x16.
// Scan (round 6): chunk-parallel two-pass linear scan. Thread-per-d, h[16] in
// VGPRs (no shuffles), 16 chunks of 64 steps, B/C via LDS b128 broadcasts,
// global loads double-buffered in 8-step groups. S,P alias gout; Hin aliases
// inw (disjoint lifetimes).

typedef unsigned short u16;
typedef unsigned int u32;
typedef __bf16 bf16x8 __attribute__((ext_vector_type(8)));
typedef float f32x4 __attribute__((ext_vector_type(4)));
typedef u32 u32x4 __attribute__((ext_vector_type(4)));

#define L_SEQ 1024
#define DM 768
#define DI 1536
#define DS 16
#define DTR 48
#define M_TOK 2048
#define TCH 64
#define NCH (L_SEQ / TCH)  // 16

__device__ __forceinline__ float bf2f(u16 u) {
  union { u32 i; float f; } v; v.i = ((u32)u) << 16; return v.f;
}
__device__ __forceinline__ u16 f2bf(float f) {
  union { float f; u32 i; } v; v.f = f;
  u32 r = v.i + 0x7fffu + ((v.i >> 16) & 1u);   // RNE
  return (u16)(r >> 16);
}

__device__ __forceinline__ void llds16(const void* g, void* l) {
  __builtin_amdgcn_global_load_lds((__attribute__((address_space(1))) void*)g,
                                   (__attribute__((address_space(3))) void*)l, 16, 0, 0);
}

// ---------------- fp32 -> bf16 convert (GEMM weights) ----------------------
__launch_bounds__(256)
__global__ void k_cvt(const float* __restrict__ in, u16* __restrict__ out, int n) {
  const int i = blockIdx.x * 256 + threadIdx.x;
  if (i < n) out[i] = f2bf(in[i]);
}

// ---------------- LayerNorm ------------------------------------------------
__launch_bounds__(256)
__global__ void k_ln(const float* __restrict__ x, const float* __restrict__ g,
                     const float* __restrict__ b, u16* __restrict__ x0) {
  const int tok = blockIdx.x;
  const int tid = threadIdx.x;
  const float e0 = x[tok * DM + tid];
  const float e1 = x[tok * DM + tid + 256];
  const float e2 = x[tok * DM + tid + 512];
  float s = e0 + e1 + e2;
  float s2 = e0 * e0 + e1 * e1 + e2 * e2;
#pragma unroll
  for (int off = 1; off < 64; off <<= 1) {
    s += __shfl_xor(s, off, 64);
    s2 += __shfl_xor(s2, off, 64);
  }
  __shared__ float rs[4], rq[4];
  const int wave = tid >> 6, lane = tid & 63;
  if (lane == 0) { rs[wave] = s; rq[wave] = s2; }
  __syncthreads();
  s = rs[0] + rs[1] + rs[2] + rs[3];
  s2 = rq[0] + rq[1] + rq[2] + rq[3];
  const float mean = s * (1.0f / DM);
  const float var = s2 * (1.0f / DM) - mean * mean;
  const float inv = rsqrtf(var + 1e-5f);
  x0[tok * DM + tid]       = f2bf((e0 - mean) * inv * g[tid]       + b[tid]);
  x0[tok * DM + tid + 256] = f2bf((e1 - mean) * inv * g[tid + 256] + b[tid + 256]);
  x0[tok * DM + tid + 512] = f2bf((e2 - mean) * inv * g[tid + 512] + b[tid + 512]);
}

// ---------------- weight padding ------------------------------------------
__launch_bounds__(256)
__global__ void k_pad_xproj(const float* __restrict__ w0, const float* __restrict__ w1,
                            u16* __restrict__ o0, u16* __restrict__ o1) {
  const int dir = blockIdx.z;
  const float* w = dir ? w1 : w0;
  u16* o = dir ? o1 : o0;
  const int col = blockIdx.x * 256 + threadIdx.x;
  const int row = blockIdx.y;
  o[row * DI + col] = (row < 80) ? f2bf(w[row * DI + col]) : (u16)0;
}
__launch_bounds__(256)
__global__ void k_pad_dtw(const float* __restrict__ w0, const float* __restrict__ w1,
                          u16* __restrict__ o0, u16* __restrict__ o1) {
  const int dir = blockIdx.y;
  const float* w = dir ? w1 : w0;
  u16* o = dir ? o1 : o0;
  const int idx = blockIdx.x * 256 + threadIdx.x;
  const int row = idx >> 6, col = idx & 63;
  o[idx] = (col < DTR) ? f2bf(w[row * DTR + col]) : (u16)0;
}

// ---------------- GEMM (unchanged from round 5) ---------------------------
template <int MODE>
__launch_bounds__(256)
__global__ void k_gemm(const u16* __restrict__ A0, const u16* __restrict__ A1,
                       const u16* __restrict__ W0, const u16* __restrict__ W1,
                       float* __restrict__ C0, float* __restrict__ C1,
                       const float* __restrict__ b0, const float* __restrict__ b1,
                       u16* __restrict__ aux0, u16* __restrict__ aux1,
                       int N, int K, int flip1) {
  const int dir = blockIdx.z;
  const u16* A = dir ? A1 : A0;
  const u16* W = dir ? W1 : W0;
  float* C = dir ? C1 : C0;
  const float* bias = dir ? b1 : b0;
  u16* aux = dir ? aux1 : aux0;
  const int doflip = flip1 & dir;

  __shared__ __align__(16) u16 sA[128 * 32];
  __shared__ __align__(16) u16 sB[128 * 32];

  const int tid = threadIdx.x;
  const int lane = tid & 63, wave = tid >> 6;
  const int m0 = blockIdx.y * 128, n0 = blockIdx.x * 128;

  const f32x4 vzero = {0.f, 0.f, 0.f, 0.f};
  f32x4 acc[4][4];
#pragma unroll
  for (int i = 0; i < 4; ++i)
#pragma unroll
    for (int j = 0; j < 4; ++j) acc[i][j] = vzero;

  const int lrow = lane & 15, kseg = lane >> 4;
  const int wm = (wave >> 1) * 64, wn = (wave & 1) * 64;

  for (int kt = 0; kt < K; kt += 32) {
    __syncthreads();
#pragma unroll
    for (int c = 0; c < 2; ++c) {
      const int q = c * 256 + tid;
      int rA = m0 + (q >> 2);
      if (doflip) rA ^= (L_SEQ - 1);
      const int kc = kt + (q & 3) * 8;
      llds16(A + (size_t)rA * K + kc, &sA[(c * 256 + wave * 64) * 8]);
      llds16(W + (size_t)(n0 + (q >> 2)) * K + kc, &sB[(c * 256 + wave * 64) * 8]);
    }
    __syncthreads();
    bf16x8 af[4], bfv[4];
#pragma unroll
    for (int i = 0; i < 4; ++i)
      af[i] = *(const bf16x8*)&sA[(wm + i * 16 + lrow) * 32 + kseg * 8];
#pragma unroll
    for (int j = 0; j < 4; ++j)
      bfv[j] = *(const bf16x8*)&sB[(wn + j * 16 + lrow) * 32 + kseg * 8];
#pragma unroll
    for (int i = 0; i < 4; ++i)
#pragma unroll
      for (int j = 0; j < 4; ++j)
        acc[i][j] = __builtin_amdgcn_mfma_f32_16x16x32_bf16(af[i], bfv[j], acc[i][j], 0, 0, 0);
  }

  const int erow = (lane >> 4) * 4, ecol = lane & 15;
#pragma unroll
  for (int i = 0; i < 4; ++i) {
#pragma unroll
    for (int j = 0; j < 4; ++j) {
#pragma unroll
      for (int r = 0; r < 4; ++r) {
        const int m = m0 + wm + i * 16 + erow + r;
        const int n = n0 + wn + j * 16 + ecol;
        float v = acc[i][j][r];
        if (MODE == 2) {
          const float xv = v + bias[n];
          v = fmaxf(xv, 0.f) + log1pf(__expf(-fabsf(xv)));
        }
        C[(size_t)m * N + n] = v;
        if (MODE == 1) {
          if (n < 64) aux[m * 64 + n] = f2bf(n < DTR ? v : 0.f);
        }
      }
    }
  }
}

// ---------------- depthwise causal conv + SiLU ----------------------------
__launch_bounds__(256)
__global__ void k_conv(const float* __restrict__ xz0, const float* __restrict__ xz1,
                       u16* __restrict__ xc0, u16* __restrict__ xc1,
                       const float* __restrict__ w0, const float* __restrict__ w1,
                       const float* __restrict__ cb0, const float* __restrict__ cb1) {
  const int dir = blockIdx.z;
  const float* xz = dir ? xz1 : xz0;
  u16* xc = dir ? xc1 : xc0;
  const float* w = dir ? w1 : w0;
  const float* cb = dir ? cb1 : cb0;
  const int d = blockIdx.x * 256 + threadIdx.x;
  const int tok = blockIdx.y;
  const int l = tok & (L_SEQ - 1);
  float s = cb[d];
#pragma unroll
  for (int j = 0; j < 4; ++j) {
    const int ls = l - 3 + j;
    if (ls >= 0) s += w[d * 4 + j] * xz[(size_t)(tok - 3 + j) * (2 * DI) + d];
  }
  const float r = s / (1.f + __expf(-s));
  xc[(size_t)tok * DI + d] = f2bf(r);
}

// ---------------- two-pass chunked scan -----------------------------------
// PASS 1: local scan from h=0 over 64-step chunk -> S[n], P[n]=prod(dA).
// PASS 2: scan from Hin, emit y=(sum_n h*C + xc*D)*silu(z) bf16.
// grid (DI/256=6, NCH=16, 4=b*2+dir); thread owns one d, h[16] in regs.
template <int PASS>
__launch_bounds__(256)
__global__ void k_scan_pass(const float* __restrict__ dl0, const float* __restrict__ dl1,
                            const u16* __restrict__ xc0, const u16* __restrict__ xc1,
                            const float* __restrict__ dbc0, const float* __restrict__ dbc1,
                            const float* __restrict__ xz0, const float* __restrict__ xz1,
                            const float* __restrict__ al0, const float* __restrict__ al1,
                            const float* __restrict__ dp0, const float* __restrict__ dp1,
                            float* __restrict__ Sb, float* __restrict__ Pb,
                            const float* __restrict__ Hin,
                            u16* __restrict__ y0, u16* __restrict__ y1) {
  const int bdir = blockIdx.z;        // b*2 + dir
  const int dir = bdir & 1, b = bdir >> 1;
  const float* delta = dir ? dl1 : dl0;
  const u16* xc = dir ? xc1 : xc0;
  const float* dbc = dir ? dbc1 : dbc0;
  const float* xz = dir ? xz1 : xz0;
  const float* alog = dir ? al1 : al0;
  const float* dpp = dir ? dp1 : dp0;
  u16* y = dir ? y1 : y0;

  const int tid = threadIdx.x;
  const int d = blockIdx.x * 256 + tid;
  const int ch = blockIdx.y;
  const size_t tb = (size_t)b * L_SEQ;
  const int t0 = ch * TCH;

  __shared__ float sBC[TCH][32];      // B(16) | C(16) per step
#pragma unroll
  for (int p = 0; p < 2; ++p) {
    const int idx = p * 256 + tid;
    const int rb = idx >> 3, cb = (idx & 7) * 4;
    *(f32x4*)&sBC[rb][cb] = *(const f32x4*)&dbc[(tb + t0 + rb) * 128 + 48 + cb];
  }

  float Af[16];
#pragma unroll
  for (int q = 0; q < 4; ++q) {
    const f32x4 a = *(const f32x4*)&alog[d * DS + q * 4];
#pragma unroll
    for (int j = 0; j < 4; ++j) Af[q * 4 + j] = -__expf(a[j]);
  }

  float h[16], Pp[16];
  if (PASS == 1) {
#pragma unroll
    for (int n = 0; n < 16; ++n) { h[n] = 0.f; Pp[n] = 1.f; }
  } else {
#pragma unroll
    for (int n = 0; n < 16; ++n)
      h[n] = Hin[(((size_t)bdir * NCH + ch) * 16 + n) * DI + d];
  }
  const float Dv = (PASS == 2) ? dpp[d] : 0.f;

  __syncthreads();

  float dbuf[2][8], zbuf[2][8];
  u16 xbuf[2][8];
#define TLOAD(g, bu)                                                      \
  {                                                                       \
    _Pragma("unroll") for (int i = 0; i < 8; ++i) {                       \
      const size_t row = tb + t0 + (g) * 8 + i;                           \
      dbuf[bu][i] = delta[row * DI + d];                                  \
      xbuf[bu][i] = xc[row * DI + d];                                     \
      if (PASS == 2) zbuf[bu][i] = xz[row * (2 * DI) + DI + d];           \
    }                                                                     \
  }
  TLOAD(0, 0)
#pragma unroll
  for (int g = 0; g < 8; ++g) {
    if (g < 7) TLOAD(g + 1, (g + 1) & 1)
    const int bu = g & 1;
#pragma unroll
    for (int i = 0; i < 8; ++i) {
      const int t = g * 8 + i;
      const float dlt = dbuf[bu][i];
      const float xcv = bf2f(xbuf[bu][i]);
      const float dbx = dlt * xcv;
      float Bv[16], Cv[16];
#pragma unroll
      for (int q = 0; q < 4; ++q)
        *(f32x4*)&Bv[q * 4] = *(const f32x4*)&sBC[t][q * 4];
      if (PASS == 2) {
#pragma unroll
        for (int q = 0; q < 4; ++q)
          *(f32x4*)&Cv[q * 4] = *(const f32x4*)&sBC[t][16 + q * 4];
      }
      float yv = 0.f;
#pragma unroll
      for (int n = 0; n < 16; ++n) {
        const float dA = __expf(dlt * Af[n]);
        if (PASS == 1) Pp[n] *= dA;
        h[n] = fmaf(dA, h[n], Bv[n] * dbx);
        if (PASS == 2) yv = fmaf(h[n], Cv[n], yv);
      }
      if (PASS == 2) {
        const float zv = zbuf[bu][i];
        const float sz = zv / (1.f + __expf(-zv));
        y[(tb + t0 + t) * DI + d] = f2bf((yv + xcv * Dv) * sz);
      }
    }
  }
#undef TLOAD

  if (PASS == 1) {
#pragma unroll
    for (int n = 0; n < 16; ++n) {
      const size_t o = (((size_t)bdir * NCH + ch) * 16 + n) * DI + d;
      Sb[o] = h[n];
      Pb[o] = Pp[n];
    }
  }
}

// combine: sequential over 16 chunks per (bdir,n,d); writes Hin (state
// entering each chunk). 98304 threads, d fastest -> coalesced.
__launch_bounds__(256)
__global__ void k_comb(const float* __restrict__ Sb, const float* __restrict__ Pb,
                       float* __restrict__ Hin) {
  const int gid = blockIdx.x * 256 + threadIdx.x;  // 64*1536
  const int d = gid % DI;
  const int bn = gid / DI;            // bdir*16 + n
  const int bdir = bn >> 4, n = bn & 15;
  float H = 0.f;
#pragma unroll
  for (int c = 0; c < NCH; ++c) {
    const size_t o = (((size_t)bdir * NCH + c) * 16 + n) * DI + d;
    Hin[o] = H;
    H = fmaf(Pb[o], H, Sb[o]);
  }
}

// ---------------- final residual ------------------------------------------
__launch_bounds__(256)
__global__ void k_final(const float* __restrict__ x, const float* __restrict__ g0,
                        const float* __restrict__ g1, float* __restrict__ out) {
  const int c = blockIdx.x * 256 + threadIdx.x;
  const int tok = blockIdx.y;
  const int ftok = tok ^ (L_SEQ - 1);
  const size_t i = (size_t)tok * DM + c;
  out[i] = x[i] + g0[i] + g1[(size_t)ftok * DM + c];
}

extern "C" void kernel_launch(void* const* d_in, const int* in_sizes, int n_in,
                              void* d_out, int out_size, void* d_ws, size_t ws_size,
                              hipStream_t stream) {
  (void)n_in; (void)out_size; (void)in_sizes;
  const float* x      = (const float*)d_in[0];
  const float* ln_g   = (const float*)d_in[1];
  const float* ln_b   = (const float*)d_in[2];
  const float* in_w_f[2]  = {(const float*)d_in[3],  (const float*)d_in[12]};
  const float* conv_w[2]  = {(const float*)d_in[4],  (const float*)d_in[13]};
  const float* conv_b[2]  = {(const float*)d_in[5],  (const float*)d_in[14]};
  const float* xproj_w[2] = {(const float*)d_in[6],  (const float*)d_in[15]};
  const float* dt_w[2]    = {(const float*)d_in[7],  (const float*)d_in[16]};
  const float* dt_b[2]    = {(const float*)d_in[8],  (const float*)d_in[17]};
  const float* A_log[2]   = {(const float*)d_in[9],  (const float*)d_in[18]};
  const float* Dp[2]      = {(const float*)d_in[10], (const float*)d_in[19]};
  const float* out_w_f[2] = {(const float*)d_in[11], (const float*)d_in[20]};

  char* ws = (char*)d_ws;
  size_t off = 0;
  auto alloc = [&](size_t bytes) {
    void* p = ws + off;
    off = (off + bytes + 255) & ~(size_t)255;
    return p;
  };

  u16* inw[2];  for (int i = 0; i < 2; ++i) inw[i]  = (u16*)alloc((size_t)2 * DI * DM * 2);
  u16* outw[2]; for (int i = 0; i < 2; ++i) outw[i] = (u16*)alloc((size_t)DM * DI * 2);
  u16* x0 = (u16*)alloc((size_t)M_TOK * DM * 2);
  float* xz[2];   for (int i = 0; i < 2; ++i) xz[i]   = (float*)alloc((size_t)M_TOK * 2 * DI * 4);
  u16* xc[2];     for (int i = 0; i < 2; ++i) xc[i]   = (u16*)alloc((size_t)M_TOK * DI * 2);
  float* dbc[2];  for (int i = 0; i < 2; ++i) dbc[i]  = (float*)alloc((size_t)M_TOK * 128 * 4);
  u16* dtin[2];   for (int i = 0; i < 2; ++i) dtin[i] = (u16*)alloc((size_t)M_TOK * 64 * 2);
  float* dlt[2];  for (int i = 0; i < 2; ++i) dlt[i]  = (float*)alloc((size_t)M_TOK * DI * 4);
  u16* yb[2];     for (int i = 0; i < 2; ++i) yb[i]   = (u16*)alloc((size_t)M_TOK * DI * 2);
  float* gout[2]; for (int i = 0; i < 2; ++i) gout[i] = (float*)alloc((size_t)M_TOK * DM * 4);
  u16* xpw[2];    for (int i = 0; i < 2; ++i) xpw[i]  = (u16*)alloc((size_t)128 * DI * 2);
  u16* dtwp[2];   for (int i = 0; i < 2; ++i) dtwp[i] = (u16*)alloc((size_t)DI * 64 * 2);

  // scan scratch ALIASED (disjoint lifetimes):
  //   S,P (4*16*16*DI floats = 6.29 MB each) alias gout[0]/gout[1]
  //   (gout written only by out-proj, after combine consumed S,P).
  //   Hin (6.29 MB) aliases inw[0..] (dead after in-proj GEMM; 9.44 MB).
  float* Sb  = gout[0];
  float* Pb  = gout[1];
  float* Hin = (float*)inw[0];

  if (off > ws_size) return;  // sentinel: zero output -> absmax 4.97 diag

  for (int i = 0; i < 2; ++i) {
    k_cvt<<<dim3((2 * DI * DM + 255) / 256), dim3(256), 0, stream>>>(in_w_f[i], inw[i], 2 * DI * DM);
    k_cvt<<<dim3((DM * DI + 255) / 256), dim3(256), 0, stream>>>(out_w_f[i], outw[i], DM * DI);
  }

  k_ln<<<dim3(M_TOK), dim3(256), 0, stream>>>(x, ln_g, ln_b, x0);
  k_pad_xproj<<<dim3(6, 128, 2), dim3(256), 0, stream>>>(xproj_w[0], xproj_w[1], xpw[0], xpw[1]);
  k_pad_dtw<<<dim3(384, 2), dim3(256), 0, stream>>>(dt_w[0], dt_w[1], dtwp[0], dtwp[1]);
  k_gemm<0><<<dim3(24, 16, 2), dim3(256), 0, stream>>>(
      x0, x0, inw[0], inw[1], xz[0], xz[1], nullptr, nullptr, nullptr, nullptr,
      2 * DI, DM, 1);
  k_conv<<<dim3(6, M_TOK, 2), dim3(256), 0, stream>>>(
      xz[0], xz[1], xc[0], xc[1], conv_w[0], conv_w[1], conv_b[0], conv_b[1]);
  k_gemm<1><<<dim3(1, 16, 2), dim3(256), 0, stream>>>(
      xc[0], xc[1], xpw[0], xpw[1], dbc[0], dbc[1], nullptr, nullptr, dtin[0], dtin[1],
      128, DI, 0);
  k_gemm<2><<<dim3(12, 16, 2), dim3(256), 0, stream>>>(
      dtin[0], dtin[1], dtwp[0], dtwp[1], dlt[0], dlt[1], dt_b[0], dt_b[1], nullptr, nullptr,
      DI, 64, 0);
  // two-pass scan
  k_scan_pass<1><<<dim3(6, NCH, 4), dim3(256), 0, stream>>>(
      dlt[0], dlt[1], xc[0], xc[1], dbc[0], dbc[1], xz[0], xz[1],
      A_log[0], A_log[1], Dp[0], Dp[1], Sb, Pb, nullptr, nullptr, nullptr);
  k_comb<<<dim3(384), dim3(256), 0, stream>>>(Sb, Pb, Hin);
  k_scan_pass<2><<<dim3(6, NCH, 4), dim3(256), 0, stream>>>(
      dlt[0], dlt[1], xc[0], xc[1], dbc[0], dbc[1], xz[0], xz[1],
      A_log[0], A_log[1], Dp[0], Dp[1], Sb, Pb, Hin, yb[0], yb[1]);
  k_gemm<0><<<dim3(6, 16, 2), dim3(256), 0, stream>>>(
      yb[0], yb[1], outw[0], outw[1], gout[0], gout[1], nullptr, nullptr, nullptr, nullptr,
      DM, DI, 0);
  k_final<<<dim3(3, M_TOK), dim3(256), 0, stream>>>(x, gout[0], gout[1], (float*)d_out);
}

// Round 7
// 447.311 us; speedup vs baseline: 1.5606x; 1.1627x over previous
//
#include <hip/hip_runtime.h>

// BiMambaBlock on gfx950. Inputs fp32 (bf16-valued), output fp32.
// GEMMs: bf16 MFMA 16x16x32, 128x128 tile, BK=32, async global_load_lds x16.
// Scan: chunk-parallel two-pass linear scan, thread-per-d, h[16] in VGPRs.
// Round 7 diff vs round 6: de-spilled scan passes (VGPR 256+spill -> ~90):
// quad-wise B/C consumption from LDS, rolled 4-step group loop w/ explicit
// double buffer, 64-thread single-wave blocks, __launch_bounds__(64,4).

typedef unsigned short u16;
typedef unsigned int u32;
typedef __bf16 bf16x8 __attribute__((ext_vector_type(8)));
typedef float f32x4 __attribute__((ext_vector_type(4)));
typedef u32 u32x4 __attribute__((ext_vector_type(4)));

#define L_SEQ 1024
#define DM 768
#define DI 1536
#define DS 16
#define DTR 48
#define M_TOK 2048
#define TCH 64
#define NCH (L_SEQ / TCH)  // 16
#define GP 4               // steps per load group in scan

__device__ __forceinline__ float bf2f(u16 u) {
  union { u32 i; float f; } v; v.i = ((u32)u) << 16; return v.f;
}
__device__ __forceinline__ u16 f2bf(float f) {
  union { float f; u32 i; } v; v.f = f;
  u32 r = v.i + 0x7fffu + ((v.i >> 16) & 1u);   // RNE
  return (u16)(r >> 16);
}

__device__ __forceinline__ void llds16(const void* g, void* l) {
  __builtin_amdgcn_global_load_lds((__attribute__((address_space(1))) void*)g,
                                   (__attribute__((address_space(3))) void*)l, 16, 0, 0);
}

// ---------------- fp32 -> bf16 convert (GEMM weights) ----------------------
__launch_bounds__(256)
__global__ void k_cvt(const float* __restrict__ in, u16* __restrict__ out, int n) {
  const int i = blockIdx.x * 256 + threadIdx.x;
  if (i < n) out[i] = f2bf(in[i]);
}

// ---------------- LayerNorm ------------------------------------------------
__launch_bounds__(256)
__global__ void k_ln(const float* __restrict__ x, const float* __restrict__ g,
                     const float* __restrict__ b, u16* __restrict__ x0) {
  const int tok = blockIdx.x;
  const int tid = threadIdx.x;
  const float e0 = x[tok * DM + tid];
  const float e1 = x[tok * DM + tid + 256];
  const float e2 = x[tok * DM + tid + 512];
  float s = e0 + e1 + e2;
  float s2 = e0 * e0 + e1 * e1 + e2 * e2;
#pragma unroll
  for (int off = 1; off < 64; off <<= 1) {
    s += __shfl_xor(s, off, 64);
    s2 += __shfl_xor(s2, off, 64);
  }
  __shared__ float rs[4], rq[4];
  const int wave = tid >> 6, lane = tid & 63;
  if (lane == 0) { rs[wave] = s; rq[wave] = s2; }
  __syncthreads();
  s = rs[0] + rs[1] + rs[2] + rs[3];
  s2 = rq[0] + rq[1] + rq[2] + rq[3];
  const float mean = s * (1.0f / DM);
  const float var = s2 * (1.0f / DM) - mean * mean;
  const float inv = rsqrtf(var + 1e-5f);
  x0[tok * DM + tid]       = f2bf((e0 - mean) * inv * g[tid]       + b[tid]);
  x0[tok * DM + tid + 256] = f2bf((e1 - mean) * inv * g[tid + 256] + b[tid + 256]);
  x0[tok * DM + tid + 512] = f2bf((e2 - mean) * inv * g[tid + 512] + b[tid + 512]);
}

// ---------------- weight padding ------------------------------------------
__launch_bounds__(256)
__global__ void k_pad_xproj(const float* __restrict__ w0, const float* __restrict__ w1,
                            u16* __restrict__ o0, u16* __restrict__ o1) {
  const int dir = blockIdx.z;
  const float* w = dir ? w1 : w0;
  u16* o = dir ? o1 : o0;
  const int col = blockIdx.x * 256 + threadIdx.x;
  const int row = blockIdx.y;
  o[row * DI + col] = (row < 80) ? f2bf(w[row * DI + col]) : (u16)0;
}
__launch_bounds__(256)
__global__ void k_pad_dtw(const float* __restrict__ w0, const float* __restrict__ w1,
                          u16* __restrict__ o0, u16* __restrict__ o1) {
  const int dir = blockIdx.y;
  const float* w = dir ? w1 : w0;
  u16* o = dir ? o1 : o0;
  const int idx = blockIdx.x * 256 + threadIdx.x;
  const int row = idx >> 6, col = idx & 63;
  o[idx] = (col < DTR) ? f2bf(w[row * DTR + col]) : (u16)0;
}

// ---------------- GEMM (unchanged) ----------------------------------------
template <int MODE>
__launch_bounds__(256)
__global__ void k_gemm(const u16* __restrict__ A0, const u16* __restrict__ A1,
                       const u16* __restrict__ W0, const u16* __restrict__ W1,
                       float* __restrict__ C0, float* __restrict__ C1,
                       const float* __restrict__ b0, const float* __restrict__ b1,
                       u16* __restrict__ aux0, u16* __restrict__ aux1,
                       int N, int K, int flip1) {
  const int dir = blockIdx.z;
  const u16* A = dir ? A1 : A0;
  const u16* W = dir ? W1 : W0;
  float* C = dir ? C1 : C0;
  const float* bias = dir ? b1 : b0;
  u16* aux = dir ? aux1 : aux0;
  const int doflip = flip1 & dir;

  __shared__ __align__(16) u16 sA[128 * 32];
  __shared__ __align__(16) u16 sB[128 * 32];

  const int tid = threadIdx.x;
  const int lane = tid & 63, wave = tid >> 6;
  const int m0 = blockIdx.y * 128, n0 = blockIdx.x * 128;

  const f32x4 vzero = {0.f, 0.f, 0.f, 0.f};
  f32x4 acc[4][4];
#pragma unroll
  for (int i = 0; i < 4; ++i)
#pragma unroll
    for (int j = 0; j < 4; ++j) acc[i][j] = vzero;

  const int lrow = lane & 15, kseg = lane >> 4;
  const int wm = (wave >> 1) * 64, wn = (wave & 1) * 64;

  for (int kt = 0; kt < K; kt += 32) {
    __syncthreads();
#pragma unroll
    for (int c = 0; c < 2; ++c) {
      const int q = c * 256 + tid;
      int rA = m0 + (q >> 2);
      if (doflip) rA ^= (L_SEQ - 1);
      const int kc = kt + (q & 3) * 8;
      llds16(A + (size_t)rA * K + kc, &sA[(c * 256 + wave * 64) * 8]);
      llds16(W + (size_t)(n0 + (q >> 2)) * K + kc, &sB[(c * 256 + wave * 64) * 8]);
    }
    __syncthreads();
    bf16x8 af[4], bfv[4];
#pragma unroll
    for (int i = 0; i < 4; ++i)
      af[i] = *(const bf16x8*)&sA[(wm + i * 16 + lrow) * 32 + kseg * 8];
#pragma unroll
    for (int j = 0; j < 4; ++j)
      bfv[j] = *(const bf16x8*)&sB[(wn + j * 16 + lrow) * 32 + kseg * 8];
#pragma unroll
    for (int i = 0; i < 4; ++i)
#pragma unroll
      for (int j = 0; j < 4; ++j)
        acc[i][j] = __builtin_amdgcn_mfma_f32_16x16x32_bf16(af[i], bfv[j], acc[i][j], 0, 0, 0);
  }

  const int erow = (lane >> 4) * 4, ecol = lane & 15;
#pragma unroll
  for (int i = 0; i < 4; ++i) {
#pragma unroll
    for (int j = 0; j < 4; ++j) {
#pragma unroll
      for (int r = 0; r < 4; ++r) {
        const int m = m0 + wm + i * 16 + erow + r;
        const int n = n0 + wn + j * 16 + ecol;
        float v = acc[i][j][r];
        if (MODE == 2) {
          const float xv = v + bias[n];
          v = fmaxf(xv, 0.f) + log1pf(__expf(-fabsf(xv)));
        }
        C[(size_t)m * N + n] = v;
        if (MODE == 1) {
          if (n < 64) aux[m * 64 + n] = f2bf(n < DTR ? v : 0.f);
        }
      }
    }
  }
}

// ---------------- depthwise causal conv + SiLU ----------------------------
__launch_bounds__(256)
__global__ void k_conv(const float* __restrict__ xz0, const float* __restrict__ xz1,
                       u16* __restrict__ xc0, u16* __restrict__ xc1,
                       const float* __restrict__ w0, const float* __restrict__ w1,
                       const float* __restrict__ cb0, const float* __restrict__ cb1) {
  const int dir = blockIdx.z;
  const float* xz = dir ? xz1 : xz0;
  u16* xc = dir ? xc1 : xc0;
  const float* w = dir ? w1 : w0;
  const float* cb = dir ? cb1 : cb0;
  const int d = blockIdx.x * 256 + threadIdx.x;
  const int tok = blockIdx.y;
  const int l = tok & (L_SEQ - 1);
  float s = cb[d];
#pragma unroll
  for (int j = 0; j < 4; ++j) {
    const int ls = l - 3 + j;
    if (ls >= 0) s += w[d * 4 + j] * xz[(size_t)(tok - 3 + j) * (2 * DI) + d];
  }
  const float r = s / (1.f + __expf(-s));
  xc[(size_t)tok * DI + d] = f2bf(r);
}

// ---------------- two-pass chunked scan (de-spilled) ----------------------
// PASS 1: local scan from h=0 over TCH steps -> S[n], P[n]=prod(dA).
// PASS 2: scan from Hin, emit y=(sum_n h*C + xc*D)*silu(z) bf16.
// block = 64 thr (one wave, 64 d-channels); grid (DI/64=24, NCH, 4=b*2+dir).
template <int PASS>
__launch_bounds__(64, 4)
__global__ void k_scan_pass(const float* __restrict__ dl0, const float* __restrict__ dl1,
                            const u16* __restrict__ xc0, const u16* __restrict__ xc1,
                            const float* __restrict__ dbc0, const float* __restrict__ dbc1,
                            const float* __restrict__ xz0, const float* __restrict__ xz1,
                            const float* __restrict__ al0, const float* __restrict__ al1,
                            const float* __restrict__ dp0, const float* __restrict__ dp1,
                            float* __restrict__ Sb, float* __restrict__ Pb,
                            const float* __restrict__ Hin,
                            u16* __restrict__ y0, u16* __restrict__ y1) {
  const int bdir = blockIdx.z;        // b*2 + dir
  const int dir = bdir & 1, b = bdir >> 1;
  const float* delta = dir ? dl1 : dl0;
  const u16* xc = dir ? xc1 : xc0;
  const float* dbc = dir ? dbc1 : dbc0;
  const float* xz = dir ? xz1 : xz0;
  const float* alog = dir ? al1 : al0;
  const float* dpp = dir ? dp1 : dp0;
  u16* y = dir ? y1 : y0;

  const int tid = threadIdx.x;
  const int d = blockIdx.x * 64 + tid;
  const int ch = blockIdx.y;
  const size_t tb = (size_t)b * L_SEQ;
  const int t0 = ch * TCH;

  __shared__ float sBC[TCH][32];      // B(16) | C(16) per step
#pragma unroll
  for (int p = 0; p < 8; ++p) {
    const int idx = p * 64 + tid;
    const int rb = idx >> 3, cb = (idx & 7) * 4;
    *(f32x4*)&sBC[rb][cb] = *(const f32x4*)&dbc[(tb + t0 + rb) * 128 + 48 + cb];
  }

  float Af[16];
#pragma unroll
  for (int q = 0; q < 4; ++q) {
    const f32x4 a = *(const f32x4*)&alog[d * DS + q * 4];
#pragma unroll
    for (int j = 0; j < 4; ++j) Af[q * 4 + j] = -__expf(a[j]);
  }

  float h[16], Pp[16];
  if (PASS == 1) {
#pragma unroll
    for (int n = 0; n < 16; ++n) { h[n] = 0.f; Pp[n] = 1.f; }
  } else {
#pragma unroll
    for (int n = 0; n < 16; ++n)
      h[n] = Hin[(((size_t)bdir * NCH + ch) * 16 + n) * DI + d];
  }
  const float Dv = (PASS == 2) ? dpp[d] : 0.f;

  __syncthreads();

  float db[2][GP], zb[2][GP];
  u16 xb[2][GP];
#define TLOAD(g, bu)                                                      \
  {                                                                       \
    _Pragma("unroll") for (int i = 0; i < GP; ++i) {                      \
      const size_t row = tb + t0 + (g) * GP + i;                          \
      db[bu][i] = delta[row * DI + d];                                    \
      xb[bu][i] = xc[row * DI + d];                                       \
      if (PASS == 2) zb[bu][i] = xz[row * (2 * DI) + DI + d];             \
    }                                                                     \
  }
  TLOAD(0, 0)
#pragma unroll 1
  for (int g = 0; g < TCH / GP; ++g) {
    const int bu = g & 1;
    if (g + 1 < TCH / GP) TLOAD(g + 1, bu ^ 1)
#pragma unroll
    for (int i = 0; i < GP; ++i) {
      const int t = g * GP + i;
      const float dlt = db[bu][i];
      const float xcv = bf2f(xb[bu][i]);
      const float dbx = dlt * xcv;
      float yv = 0.f;
#pragma unroll
      for (int q = 0; q < 4; ++q) {
        const f32x4 B4 = *(const f32x4*)&sBC[t][q * 4];
        f32x4 C4;
        if (PASS == 2) C4 = *(const f32x4*)&sBC[t][16 + q * 4];
#pragma unroll
        for (int j = 0; j < 4; ++j) {
          const int n = q * 4 + j;
          const float dA = __expf(dlt * Af[n]);
          if (PASS == 1) Pp[n] *= dA;
          h[n] = fmaf(dA, h[n], B4[j] * dbx);
          if (PASS == 2) yv = fmaf(h[n], C4[j], yv);
        }
      }
      if (PASS == 2) {
        const float zv = zb[bu][i];
        const float sz = zv / (1.f + __expf(-zv));
        y[(tb + t0 + t) * DI + d] = f2bf((yv + xcv * Dv) * sz);
      }
    }
  }
#undef TLOAD

  if (PASS == 1) {
#pragma unroll
    for (int n = 0; n < 16; ++n) {
      const size_t o = (((size_t)bdir * NCH + ch) * 16 + n) * DI + d;
      Sb[o] = h[n];
      Pb[o] = Pp[n];
    }
  }
}

// combine: sequential over 16 chunks per (bdir,n,d); writes Hin.
__launch_bounds__(256)
__global__ void k_comb(const float* __restrict__ Sb, const float* __restrict__ Pb,
                       float* __restrict__ Hin) {
  const int gid = blockIdx.x * 256 + threadIdx.x;  // 64*1536
  const int d = gid % DI;
  const int bn = gid / DI;            // bdir*16 + n
  const int bdir = bn >> 4, n = bn & 15;
  float H = 0.f;
#pragma unroll
  for (int c = 0; c < NCH; ++c) {
    const size_t o = (((size_t)bdir * NCH + c) * 16 + n) * DI + d;
    Hin[o] = H;
    H = fmaf(Pb[o], H, Sb[o]);
  }
}

// ---------------- final residual ------------------------------------------
__launch_bounds__(256)
__global__ void k_final(const float* __restrict__ x, const float* __restrict__ g0,
                        const float* __restrict__ g1, float* __restrict__ out) {
  const int c = blockIdx.x * 256 + threadIdx.x;
  const int tok = blockIdx.y;
  const int ftok = tok ^ (L_SEQ - 1);
  const size_t i = (size_t)tok * DM + c;
  out[i] = x[i] + g0[i] + g1[(size_t)ftok * DM + c];
}

extern "C" void kernel_launch(void* const* d_in, const int* in_sizes, int n_in,
                              void* d_out, int out_size, void* d_ws, size_t ws_size,
                              hipStream_t stream) {
  (void)n_in; (void)out_size; (void)in_sizes;
  const float* x      = (const float*)d_in[0];
  const float* ln_g   = (const float*)d_in[1];
  const float* ln_b   = (const float*)d_in[2];
  const float* in_w_f[2]  = {(const float*)d_in[3],  (const float*)d_in[12]};
  const float* conv_w[2]  = {(const float*)d_in[4],  (const float*)d_in[13]};
  const float* conv_b[2]  = {(const float*)d_in[5],  (const float*)d_in[14]};
  const float* xproj_w[2] = {(const float*)d_in[6],  (const float*)d_in[15]};
  const float* dt_w[2]    = {(const float*)d_in[7],  (const float*)d_in[16]};
  const float* dt_b[2]    = {(const float*)d_in[8],  (const float*)d_in[17]};
  const float* A_log[2]   = {(const float*)d_in[9],  (const float*)d_in[18]};
  const float* Dp[2]      = {(const float*)d_in[10], (const float*)d_in[19]};
  const float* out_w_f[2] = {(const float*)d_in[11], (const float*)d_in[20]};

  char* ws = (char*)d_ws;
  size_t off = 0;
  auto alloc = [&](size_t bytes) {
    void* p = ws + off;
    off = (off + bytes + 255) & ~(size_t)255;
    return p;
  };

  u16* inw[2];  for (int i = 0; i < 2; ++i) inw[i]  = (u16*)alloc((size_t)2 * DI * DM * 2);
  u16* outw[2]; for (int i = 0; i < 2; ++i) outw[i] = (u16*)alloc((size_t)DM * DI * 2);
  u16* x0 = (u16*)alloc((size_t)M_TOK * DM * 2);
  float* xz[2];   for (int i = 0; i < 2; ++i) xz[i]   = (float*)alloc((size_t)M_TOK * 2 * DI * 4);
  u16* xc[2];     for (int i = 0; i < 2; ++i) xc[i]   = (u16*)alloc((size_t)M_TOK * DI * 2);
  float* dbc[2];  for (int i = 0; i < 2; ++i) dbc[i]  = (float*)alloc((size_t)M_TOK * 128 * 4);
  u16* dtin[2];   for (int i = 0; i < 2; ++i) dtin[i] = (u16*)alloc((size_t)M_TOK * 64 * 2);
  float* dlt[2];  for (int i = 0; i < 2; ++i) dlt[i]  = (float*)alloc((size_t)M_TOK * DI * 4);
  u16* yb[2];     for (int i = 0; i < 2; ++i) yb[i]   = (u16*)alloc((size_t)M_TOK * DI * 2);
  float* gout[2]; for (int i = 0; i < 2; ++i) gout[i] = (float*)alloc((size_t)M_TOK * DM * 4);
  u16* xpw[2];    for (int i = 0; i < 2; ++i) xpw[i]  = (u16*)alloc((size_t)128 * DI * 2);
  u16* dtwp[2];   for (int i = 0; i < 2; ++i) dtwp[i] = (u16*)alloc((size_t)DI * 64 * 2);

  // scan scratch aliased (disjoint lifetimes): S,P alias gout; Hin aliases inw
  float* Sb  = gout[0];
  float* Pb  = gout[1];
  float* Hin = (float*)inw[0];

  if (off > ws_size) return;  // sentinel: zero output -> absmax 4.97 diag

  for (int i = 0; i < 2; ++i) {
    k_cvt<<<dim3((2 * DI * DM + 255) / 256), dim3(256), 0, stream>>>(in_w_f[i], inw[i], 2 * DI * DM);
    k_cvt<<<dim3((DM * DI + 255) / 256), dim3(256), 0, stream>>>(out_w_f[i], outw[i], DM * DI);
  }

  k_ln<<<dim3(M_TOK), dim3(256), 0, stream>>>(x, ln_g, ln_b, x0);
  k_pad_xproj<<<dim3(6, 128, 2), dim3(256), 0, stream>>>(xproj_w[0], xproj_w[1], xpw[0], xpw[1]);
  k_pad_dtw<<<dim3(384, 2), dim3(256), 0, stream>>>(dt_w[0], dt_w[1], dtwp[0], dtwp[1]);
  k_gemm<0><<<dim3(24, 16, 2), dim3(256), 0, stream>>>(
      x0, x0, inw[0], inw[1], xz[0], xz[1], nullptr, nullptr, nullptr, nullptr,
      2 * DI, DM, 1);
  k_conv<<<dim3(6, M_TOK, 2), dim3(256), 0, stream>>>(
      xz[0], xz[1], xc[0], xc[1], conv_w[0], conv_w[1], conv_b[0], conv_b[1]);
  k_gemm<1><<<dim3(1, 16, 2), dim3(256), 0, stream>>>(
      xc[0], xc[1], xpw[0], xpw[1], dbc[0], dbc[1], nullptr, nullptr, dtin[0], dtin[1],
      128, DI, 0);
  k_gemm<2><<<dim3(12, 16, 2), dim3(256), 0, stream>>>(
      dtin[0], dtin[1], dtwp[0], dtwp[1], dlt[0], dlt[1], dt_b[0], dt_b[1], nullptr, nullptr,
      DI, 64, 0);
  // two-pass scan
  k_scan_pass<1><<<dim3(24, NCH, 4), dim3(64), 0, stream>>>(
      dlt[0], dlt[1], xc[0], xc[1], dbc[0], dbc[1], xz[0], xz[1],
      A_log[0], A_log[1], Dp[0], Dp[1], Sb, Pb, nullptr, nullptr, nullptr);
  k_comb<<<dim3(384), dim3(256), 0, stream>>>(Sb, Pb, Hin);
  k_scan_pass<2><<<dim3(24, NCH, 4), dim3(64), 0, stream>>>(
      dlt[0], dlt[1], xc[0], xc[1], dbc[0], dbc[1], xz[0], xz[1],
      A_log[0], A_log[1], Dp[0], Dp[1], Sb, Pb, Hin, yb[0], yb[1]);
  k_gemm<0><<<dim3(6, 16, 2), dim3(256), 0, stream>>>(
      yb[0], yb[1], outw[0], outw[1], gout[0], gout[1], nullptr, nullptr, nullptr, nullptr,
      DM, DI, 0);
  k_final<<<dim3(3, M_TOK), dim3(256), 0, stream>>>(x, gout[0], gout[1], (float*)d_out);
}

// Round 8
// 412.234 us; speedup vs baseline: 1.6934x; 1.0851x over previous
//
#include <hip/hip_runtime.h>

// BiMambaBlock on gfx950. Inputs fp32 (bf16-valued), output fp32.
// Round 8 diff vs round 7: GEMM K-loop software-pipelined via REGISTER
// prefetch (global->VGPR for tile t+1 issued right after barrier, consumed by
// ds_write next iter => vmcnt wait lands after compute; the latency is hidden
// behind MFMA/ds_read instead of serially exposed at the barrier drain).
// Manually 2x-unrolled (K % 64 == 0 for all four GEMMs). Out-proj uses BN=64
// tiles (384 blocks, was 192 under-filling 256 CUs). Scan unchanged.

typedef unsigned short u16;
typedef unsigned int u32;
typedef __bf16 bf16x8 __attribute__((ext_vector_type(8)));
typedef float f32x4 __attribute__((ext_vector_type(4)));
typedef u32 u32x4 __attribute__((ext_vector_type(4)));

#define L_SEQ 1024
#define DM 768
#define DI 1536
#define DS 16
#define DTR 48
#define M_TOK 2048
#define TCH 64
#define NCH (L_SEQ / TCH)  // 16
#define GP 4               // steps per load group in scan

__device__ __forceinline__ float bf2f(u16 u) {
  union { u32 i; float f; } v; v.i = ((u32)u) << 16; return v.f;
}
__device__ __forceinline__ u16 f2bf(float f) {
  union { float f; u32 i; } v; v.f = f;
  u32 r = v.i + 0x7fffu + ((v.i >> 16) & 1u);   // RNE
  return (u16)(r >> 16);
}

// ---------------- fp32 -> bf16 convert (GEMM weights) ----------------------
__launch_bounds__(256)
__global__ void k_cvt(const float* __restrict__ in, u16* __restrict__ out, int n) {
  const int i = blockIdx.x * 256 + threadIdx.x;
  if (i < n) out[i] = f2bf(in[i]);
}

// ---------------- LayerNorm ------------------------------------------------
__launch_bounds__(256)
__global__ void k_ln(const float* __restrict__ x, const float* __restrict__ g,
                     const float* __restrict__ b, u16* __restrict__ x0) {
  const int tok = blockIdx.x;
  const int tid = threadIdx.x;
  const float e0 = x[tok * DM + tid];
  const float e1 = x[tok * DM + tid + 256];
  const float e2 = x[tok * DM + tid + 512];
  float s = e0 + e1 + e2;
  float s2 = e0 * e0 + e1 * e1 + e2 * e2;
#pragma unroll
  for (int off = 1; off < 64; off <<= 1) {
    s += __shfl_xor(s, off, 64);
    s2 += __shfl_xor(s2, off, 64);
  }
  __shared__ float rs[4], rq[4];
  const int wave = tid >> 6, lane = tid & 63;
  if (lane == 0) { rs[wave] = s; rq[wave] = s2; }
  __syncthreads();
  s = rs[0] + rs[1] + rs[2] + rs[3];
  s2 = rq[0] + rq[1] + rq[2] + rq[3];
  const float mean = s * (1.0f / DM);
  const float var = s2 * (1.0f / DM) - mean * mean;
  const float inv = rsqrtf(var + 1e-5f);
  x0[tok * DM + tid]       = f2bf((e0 - mean) * inv * g[tid]       + b[tid]);
  x0[tok * DM + tid + 256] = f2bf((e1 - mean) * inv * g[tid + 256] + b[tid + 256]);
  x0[tok * DM + tid + 512] = f2bf((e2 - mean) * inv * g[tid + 512] + b[tid + 512]);
}

// ---------------- weight padding ------------------------------------------
__launch_bounds__(256)
__global__ void k_pad_xproj(const float* __restrict__ w0, const float* __restrict__ w1,
                            u16* __restrict__ o0, u16* __restrict__ o1) {
  const int dir = blockIdx.z;
  const float* w = dir ? w1 : w0;
  u16* o = dir ? o1 : o0;
  const int col = blockIdx.x * 256 + threadIdx.x;
  const int row = blockIdx.y;
  o[row * DI + col] = (row < 80) ? f2bf(w[row * DI + col]) : (u16)0;
}
__launch_bounds__(256)
__global__ void k_pad_dtw(const float* __restrict__ w0, const float* __restrict__ w1,
                          u16* __restrict__ o0, u16* __restrict__ o1) {
  const int dir = blockIdx.y;
  const float* w = dir ? w1 : w0;
  u16* o = dir ? o1 : o0;
  const int idx = blockIdx.x * 256 + threadIdx.x;
  const int row = idx >> 6, col = idx & 63;
  o[idx] = (col < DTR) ? f2bf(w[row * DTR + col]) : (u16)0;
}

// ---------------- GEMM: C[m,n] = sum_k A[m,k]*W[n,k], bf16 in / fp32 out ---
// BM=128, BK=32, templated BN (128 or 64), WM=64, templated WN. 256 threads =
// 4 waves in (128/64)x(BN/WN) grid. Register-prefetch pipeline, K % 64 == 0.
// MODE 0: plain store. MODE 1: + bf16 dtin[m*64+n] n<64 (0 for n>=48).
// MODE 2: softplus(acc + bias[n]).
template <int BN, int WN, int MODE>
__launch_bounds__(256)
__global__ void k_gemm(const u16* __restrict__ A0, const u16* __restrict__ A1,
                       const u16* __restrict__ W0, const u16* __restrict__ W1,
                       float* __restrict__ C0, float* __restrict__ C1,
                       const float* __restrict__ b0, const float* __restrict__ b1,
                       u16* __restrict__ aux0, u16* __restrict__ aux1,
                       int N, int K, int flip1) {
  constexpr int NWC = BN / WN;       // wave columns
  constexpr int FJ = WN / 16;        // n-frags per wave
  constexpr int CB = (BN * 32) / (256 * 8);  // B reg chunks per thread (2 or 1)

  const int dir = blockIdx.z;
  const u16* A = dir ? A1 : A0;
  const u16* W = dir ? W1 : W0;
  float* C = dir ? C1 : C0;
  const float* bias = dir ? b1 : b0;
  u16* aux = dir ? aux1 : aux0;
  const int doflip = flip1 & dir;

  __shared__ __align__(16) u16 sA[128 * 32];
  __shared__ __align__(16) u16 sB[BN * 32];

  const int tid = threadIdx.x;
  const int lane = tid & 63, wave = tid >> 6;
  const int m0 = blockIdx.y * 128, n0 = blockIdx.x * BN;

  const f32x4 vzero = {0.f, 0.f, 0.f, 0.f};
  f32x4 acc[4][FJ];
#pragma unroll
  for (int i = 0; i < 4; ++i)
#pragma unroll
    for (int j = 0; j < FJ; ++j) acc[i][j] = vzero;

  const int lrow = lane & 15, kseg = lane >> 4;
  const int wm = (wave / NWC) * 64, wn = (wave % NWC) * WN;

  u32x4 va[2][2], vb[2][CB];

#define GLOAD(s, kt)                                                          \
  {                                                                           \
    _Pragma("unroll") for (int c = 0; c < 2; ++c) {                           \
      const int q = c * 256 + tid;                                            \
      int rA = m0 + (q >> 2);                                                 \
      if (doflip) rA ^= (L_SEQ - 1);                                          \
      va[s][c] = *(const u32x4*)(A + (size_t)rA * K + (kt) + (q & 3) * 8);    \
    }                                                                         \
    _Pragma("unroll") for (int c = 0; c < CB; ++c) {                          \
      const int q = c * 256 + tid;                                            \
      vb[s][c] = *(const u32x4*)(W + (size_t)(n0 + (q >> 2)) * K + (kt) +     \
                                 (q & 3) * 8);                                \
    }                                                                         \
  }
#define SSTORE(s)                                                             \
  {                                                                           \
    _Pragma("unroll") for (int c = 0; c < 2; ++c)                             \
        *(u32x4*)&sA[(c * 256 + tid) * 8] = va[s][c];                         \
    _Pragma("unroll") for (int c = 0; c < CB; ++c)                            \
        *(u32x4*)&sB[(c * 256 + tid) * 8] = vb[s][c];                         \
  }
#define COMPUTE()                                                             \
  {                                                                           \
    bf16x8 af[4], bfv[FJ];                                                    \
    _Pragma("unroll") for (int i = 0; i < 4; ++i)                             \
        af[i] = *(const bf16x8*)&sA[(wm + i * 16 + lrow) * 32 + kseg * 8];    \
    _Pragma("unroll") for (int j = 0; j < FJ; ++j)                            \
        bfv[j] = *(const bf16x8*)&sB[(wn + j * 16 + lrow) * 32 + kseg * 8];   \
    _Pragma("unroll") for (int i = 0; i < 4; ++i)                             \
        _Pragma("unroll") for (int j = 0; j < FJ; ++j)                        \
            acc[i][j] = __builtin_amdgcn_mfma_f32_16x16x32_bf16(              \
                af[i], bfv[j], acc[i][j], 0, 0, 0);                           \
  }

  GLOAD(0, 0)
  for (int kt = 0; kt < K; kt += 64) {
    __syncthreads();
    SSTORE(0)                 // vmcnt wait for set0 lands here (after prev compute)
    __syncthreads();
    GLOAD(1, kt + 32)         // in flight during compute below
    COMPUTE()
    __syncthreads();
    SSTORE(1)
    __syncthreads();
    if (kt + 64 < K) GLOAD(0, kt + 64)
    COMPUTE()
  }
#undef GLOAD
#undef SSTORE
#undef COMPUTE

  // C/D layout: col = lane&15, row = (lane>>4)*4 + reg
  const int erow = (lane >> 4) * 4, ecol = lane & 15;
#pragma unroll
  for (int i = 0; i < 4; ++i) {
#pragma unroll
    for (int j = 0; j < FJ; ++j) {
#pragma unroll
      for (int r = 0; r < 4; ++r) {
        const int m = m0 + wm + i * 16 + erow + r;
        const int n = n0 + wn + j * 16 + ecol;
        float v = acc[i][j][r];
        if (MODE == 2) {
          const float xv = v + bias[n];
          v = fmaxf(xv, 0.f) + log1pf(__expf(-fabsf(xv)));
        }
        C[(size_t)m * N + n] = v;
        if (MODE == 1) {
          if (n < 64) aux[m * 64 + n] = f2bf(n < DTR ? v : 0.f);
        }
      }
    }
  }
}

// ---------------- depthwise causal conv + SiLU ----------------------------
__launch_bounds__(256)
__global__ void k_conv(const float* __restrict__ xz0, const float* __restrict__ xz1,
                       u16* __restrict__ xc0, u16* __restrict__ xc1,
                       const float* __restrict__ w0, const float* __restrict__ w1,
                       const float* __restrict__ cb0, const float* __restrict__ cb1) {
  const int dir = blockIdx.z;
  const float* xz = dir ? xz1 : xz0;
  u16* xc = dir ? xc1 : xc0;
  const float* w = dir ? w1 : w0;
  const float* cb = dir ? cb1 : cb0;
  const int d = blockIdx.x * 256 + threadIdx.x;
  const int tok = blockIdx.y;
  const int l = tok & (L_SEQ - 1);
  float s = cb[d];
#pragma unroll
  for (int j = 0; j < 4; ++j) {
    const int ls = l - 3 + j;
    if (ls >= 0) s += w[d * 4 + j] * xz[(size_t)(tok - 3 + j) * (2 * DI) + d];
  }
  const float r = s / (1.f + __expf(-s));
  xc[(size_t)tok * DI + d] = f2bf(r);
}

// ---------------- two-pass chunked scan (unchanged from round 7) ----------
template <int PASS>
__launch_bounds__(64, 4)
__global__ void k_scan_pass(const float* __restrict__ dl0, const float* __restrict__ dl1,
                            const u16* __restrict__ xc0, const u16* __restrict__ xc1,
                            const float* __restrict__ dbc0, const float* __restrict__ dbc1,
                            const float* __restrict__ xz0, const float* __restrict__ xz1,
                            const float* __restrict__ al0, const float* __restrict__ al1,
                            const float* __restrict__ dp0, const float* __restrict__ dp1,
                            float* __restrict__ Sb, float* __restrict__ Pb,
                            const float* __restrict__ Hin,
                            u16* __restrict__ y0, u16* __restrict__ y1) {
  const int bdir = blockIdx.z;        // b*2 + dir
  const int dir = bdir & 1, b = bdir >> 1;
  const float* delta = dir ? dl1 : dl0;
  const u16* xc = dir ? xc1 : xc0;
  const float* dbc = dir ? dbc1 : dbc0;
  const float* xz = dir ? xz1 : xz0;
  const float* alog = dir ? al1 : al0;
  const float* dpp = dir ? dp1 : dp0;
  u16* y = dir ? y1 : y0;

  const int tid = threadIdx.x;
  const int d = blockIdx.x * 64 + tid;
  const int ch = blockIdx.y;
  const size_t tb = (size_t)b * L_SEQ;
  const int t0 = ch * TCH;

  __shared__ float sBC[TCH][32];      // B(16) | C(16) per step
#pragma unroll
  for (int p = 0; p < 8; ++p) {
    const int idx = p * 64 + tid;
    const int rb = idx >> 3, cb = (idx & 7) * 4;
    *(f32x4*)&sBC[rb][cb] = *(const f32x4*)&dbc[(tb + t0 + rb) * 128 + 48 + cb];
  }

  float Af[16];
#pragma unroll
  for (int q = 0; q < 4; ++q) {
    const f32x4 a = *(const f32x4*)&alog[d * DS + q * 4];
#pragma unroll
    for (int j = 0; j < 4; ++j) Af[q * 4 + j] = -__expf(a[j]);
  }

  float h[16], Pp[16];
  if (PASS == 1) {
#pragma unroll
    for (int n = 0; n < 16; ++n) { h[n] = 0.f; Pp[n] = 1.f; }
  } else {
#pragma unroll
    for (int n = 0; n < 16; ++n)
      h[n] = Hin[(((size_t)bdir * NCH + ch) * 16 + n) * DI + d];
  }
  const float Dv = (PASS == 2) ? dpp[d] : 0.f;

  __syncthreads();

  float db[2][GP], zb[2][GP];
  u16 xb[2][GP];
#define TLOAD(g, bu)                                                      \
  {                                                                       \
    _Pragma("unroll") for (int i = 0; i < GP; ++i) {                      \
      const size_t row = tb + t0 + (g) * GP + i;                          \
      db[bu][i] = delta[row * DI + d];                                    \
      xb[bu][i] = xc[row * DI + d];                                       \
      if (PASS == 2) zb[bu][i] = xz[row * (2 * DI) + DI + d];             \
    }                                                                     \
  }
  TLOAD(0, 0)
#pragma unroll 1
  for (int g = 0; g < TCH / GP; ++g) {
    const int bu = g & 1;
    if (g + 1 < TCH / GP) TLOAD(g + 1, bu ^ 1)
#pragma unroll
    for (int i = 0; i < GP; ++i) {
      const int t = g * GP + i;
      const float dlt = db[bu][i];
      const float xcv = bf2f(xb[bu][i]);
      const float dbx = dlt * xcv;
      float yv = 0.f;
#pragma unroll
      for (int q = 0; q < 4; ++q) {
        const f32x4 B4 = *(const f32x4*)&sBC[t][q * 4];
        f32x4 C4;
        if (PASS == 2) C4 = *(const f32x4*)&sBC[t][16 + q * 4];
#pragma unroll
        for (int j = 0; j < 4; ++j) {
          const int n = q * 4 + j;
          const float dA = __expf(dlt * Af[n]);
          if (PASS == 1) Pp[n] *= dA;
          h[n] = fmaf(dA, h[n], B4[j] * dbx);
          if (PASS == 2) yv = fmaf(h[n], C4[j], yv);
        }
      }
      if (PASS == 2) {
        const float zv = zb[bu][i];
        const float sz = zv / (1.f + __expf(-zv));
        y[(tb + t0 + t) * DI + d] = f2bf((yv + xcv * Dv) * sz);
      }
    }
  }
#undef TLOAD

  if (PASS == 1) {
#pragma unroll
    for (int n = 0; n < 16; ++n) {
      const size_t o = (((size_t)bdir * NCH + ch) * 16 + n) * DI + d;
      Sb[o] = h[n];
      Pb[o] = Pp[n];
    }
  }
}

// combine: sequential over 16 chunks per (bdir,n,d); writes Hin.
__launch_bounds__(256)
__global__ void k_comb(const float* __restrict__ Sb, const float* __restrict__ Pb,
                       float* __restrict__ Hin) {
  const int gid = blockIdx.x * 256 + threadIdx.x;  // 64*1536
  const int d = gid % DI;
  const int bn = gid / DI;            // bdir*16 + n
  const int bdir = bn >> 4, n = bn & 15;
  float H = 0.f;
#pragma unroll
  for (int c = 0; c < NCH; ++c) {
    const size_t o = (((size_t)bdir * NCH + c) * 16 + n) * DI + d;
    Hin[o] = H;
    H = fmaf(Pb[o], H, Sb[o]);
  }
}

// ---------------- final residual ------------------------------------------
__launch_bounds__(256)
__global__ void k_final(const float* __restrict__ x, const float* __restrict__ g0,
                        const float* __restrict__ g1, float* __restrict__ out) {
  const int c = blockIdx.x * 256 + threadIdx.x;
  const int tok = blockIdx.y;
  const int ftok = tok ^ (L_SEQ - 1);
  const size_t i = (size_t)tok * DM + c;
  out[i] = x[i] + g0[i] + g1[(size_t)ftok * DM + c];
}

extern "C" void kernel_launch(void* const* d_in, const int* in_sizes, int n_in,
                              void* d_out, int out_size, void* d_ws, size_t ws_size,
                              hipStream_t stream) {
  (void)n_in; (void)out_size; (void)in_sizes;
  const float* x      = (const float*)d_in[0];
  const float* ln_g   = (const float*)d_in[1];
  const float* ln_b   = (const float*)d_in[2];
  const float* in_w_f[2]  = {(const float*)d_in[3],  (const float*)d_in[12]};
  const float* conv_w[2]  = {(const float*)d_in[4],  (const float*)d_in[13]};
  const float* conv_b[2]  = {(const float*)d_in[5],  (const float*)d_in[14]};
  const float* xproj_w[2] = {(const float*)d_in[6],  (const float*)d_in[15]};
  const float* dt_w[2]    = {(const float*)d_in[7],  (const float*)d_in[16]};
  const float* dt_b[2]    = {(const float*)d_in[8],  (const float*)d_in[17]};
  const float* A_log[2]   = {(const float*)d_in[9],  (const float*)d_in[18]};
  const float* Dp[2]      = {(const float*)d_in[10], (const float*)d_in[19]};
  const float* out_w_f[2] = {(const float*)d_in[11], (const float*)d_in[20]};

  char* ws = (char*)d_ws;
  size_t off = 0;
  auto alloc = [&](size_t bytes) {
    void* p = ws + off;
    off = (off + bytes + 255) & ~(size_t)255;
    return p;
  };

  u16* inw[2];  for (int i = 0; i < 2; ++i) inw[i]  = (u16*)alloc((size_t)2 * DI * DM * 2);
  u16* outw[2]; for (int i = 0; i < 2; ++i) outw[i] = (u16*)alloc((size_t)DM * DI * 2);
  u16* x0 = (u16*)alloc((size_t)M_TOK * DM * 2);
  float* xz[2];   for (int i = 0; i < 2; ++i) xz[i]   = (float*)alloc((size_t)M_TOK * 2 * DI * 4);
  u16* xc[2];     for (int i = 0; i < 2; ++i) xc[i]   = (u16*)alloc((size_t)M_TOK * DI * 2);
  float* dbc[2];  for (int i = 0; i < 2; ++i) dbc[i]  = (float*)alloc((size_t)M_TOK * 128 * 4);
  u16* dtin[2];   for (int i = 0; i < 2; ++i) dtin[i] = (u16*)alloc((size_t)M_TOK * 64 * 2);
  float* dlt[2];  for (int i = 0; i < 2; ++i) dlt[i]  = (float*)alloc((size_t)M_TOK * DI * 4);
  u16* yb[2];     for (int i = 0; i < 2; ++i) yb[i]   = (u16*)alloc((size_t)M_TOK * DI * 2);
  float* gout[2]; for (int i = 0; i < 2; ++i) gout[i] = (float*)alloc((size_t)M_TOK * DM * 4);
  u16* xpw[2];    for (int i = 0; i < 2; ++i) xpw[i]  = (u16*)alloc((size_t)128 * DI * 2);
  u16* dtwp[2];   for (int i = 0; i < 2; ++i) dtwp[i] = (u16*)alloc((size_t)DI * 64 * 2);

  // scan scratch aliased (disjoint lifetimes): S,P alias gout; Hin aliases inw
  float* Sb  = gout[0];
  float* Pb  = gout[1];
  float* Hin = (float*)inw[0];

  if (off > ws_size) return;  // sentinel: zero output -> absmax 4.97 diag

  for (int i = 0; i < 2; ++i) {
    k_cvt<<<dim3((2 * DI * DM + 255) / 256), dim3(256), 0, stream>>>(in_w_f[i], inw[i], 2 * DI * DM);
    k_cvt<<<dim3((DM * DI + 255) / 256), dim3(256), 0, stream>>>(out_w_f[i], outw[i], DM * DI);
  }

  k_ln<<<dim3(M_TOK), dim3(256), 0, stream>>>(x, ln_g, ln_b, x0);
  k_pad_xproj<<<dim3(6, 128, 2), dim3(256), 0, stream>>>(xproj_w[0], xproj_w[1], xpw[0], xpw[1]);
  k_pad_dtw<<<dim3(384, 2), dim3(256), 0, stream>>>(dt_w[0], dt_w[1], dtwp[0], dtwp[1]);
  // in-proj: xz = x0 @ in_w^T (dir1 reads row^1023)
  k_gemm<128, 64, 0><<<dim3(24, 16, 2), dim3(256), 0, stream>>>(
      x0, x0, inw[0], inw[1], xz[0], xz[1], nullptr, nullptr, nullptr, nullptr,
      2 * DI, DM, 1);
  k_conv<<<dim3(6, M_TOK, 2), dim3(256), 0, stream>>>(
      xz[0], xz[1], xc[0], xc[1], conv_w[0], conv_w[1], conv_b[0], conv_b[1]);
  // x-proj: dbc = xc @ xproj^T (N padded 128), fused dtin extraction
  k_gemm<128, 64, 1><<<dim3(1, 16, 2), dim3(256), 0, stream>>>(
      xc[0], xc[1], xpw[0], xpw[1], dbc[0], dbc[1], nullptr, nullptr, dtin[0], dtin[1],
      128, DI, 0);
  // dt-proj: delta = softplus(dtin @ dt_w^T + dt_b) (K padded 64)
  k_gemm<128, 64, 2><<<dim3(12, 16, 2), dim3(256), 0, stream>>>(
      dtin[0], dtin[1], dtwp[0], dtwp[1], dlt[0], dlt[1], dt_b[0], dt_b[1], nullptr, nullptr,
      DI, 64, 0);
  // two-pass scan
  k_scan_pass<1><<<dim3(24, NCH, 4), dim3(64), 0, stream>>>(
      dlt[0], dlt[1], xc[0], xc[1], dbc[0], dbc[1], xz[0], xz[1],
      A_log[0], A_log[1], Dp[0], Dp[1], Sb, Pb, nullptr, nullptr, nullptr);
  k_comb<<<dim3(384), dim3(256), 0, stream>>>(Sb, Pb, Hin);
  k_scan_pass<2><<<dim3(24, NCH, 4), dim3(64), 0, stream>>>(
      dlt[0], dlt[1], xc[0], xc[1], dbc[0], dbc[1], xz[0], xz[1],
      A_log[0], A_log[1], Dp[0], Dp[1], Sb, Pb, Hin, yb[0], yb[1]);
  // out-proj: gout = y @ out_w^T  (BN=64 -> 384 blocks)
  k_gemm<64, 32, 0><<<dim3(12, 16, 2), dim3(256), 0, stream>>>(
      yb[0], yb[1], outw[0], outw[1], gout[0], gout[1], nullptr, nullptr, nullptr, nullptr,
      DM, DI, 0);
  k_final<<<dim3(3, M_TOK), dim3(256), 0, stream>>>(x, gout[0], gout[1], (float*)d_out);
}